// Round 1
// baseline (2817.300 us; speedup 1.0000x reference)
//
#include <hip/hip_runtime.h>
#include <hip/hip_bf16.h>

#define T_TOK 8192
#define H_DIM 2048
#define NE    16
#define TOPK  4
#define IMOE  1408
#define ISH   5632
#define TK    (T_TOK*TOPK)          // 32768 replicated rows
#define MAXTILES ((TK/128)+NE)      // 272 upper bound on grouped m-tiles

typedef __bf16 bf16;
typedef __attribute__((ext_vector_type(8))) __bf16 bf16x8;
typedef __attribute__((ext_vector_type(4))) float  f32x4;

// ---------------- async global->LDS (16B per lane, dest = wave-uniform base + lane*16)
__device__ __forceinline__ void gload_lds16(const void* g, void* l) {
  __builtin_amdgcn_global_load_lds((const __attribute__((address_space(1))) void*)g,
                                   (__attribute__((address_space(3))) void*)l, 16, 0, 0);
}

// ---------------- fp32 -> bf16 straight copy (vectorized, n % 8 == 0)
__global__ __launch_bounds__(256) void cvt_bf16_kernel(const float* __restrict__ in,
                                                       bf16* __restrict__ out, size_t n) {
  size_t i = ((size_t)blockIdx.x * 256 + threadIdx.x) * 8;
  if (i >= n) return;
  float4 v0 = *(const float4*)(in + i);
  float4 v1 = *(const float4*)(in + i + 4);
  bf16x8 o = { (bf16)v0.x,(bf16)v0.y,(bf16)v0.z,(bf16)v0.w,
               (bf16)v1.x,(bf16)v1.y,(bf16)v1.z,(bf16)v1.w };
  *(bf16x8*)(out + i) = o;
}

// ---------------- fp32 [R][C] -> bf16 [C][R] transpose (B^T layout for GEMM), dims % 32 == 0
__global__ __launch_bounds__(256) void cvt_transpose_kernel(const float* __restrict__ in,
                                                            bf16* __restrict__ out,
                                                            int R, int C,
                                                            size_t strideIn, size_t strideOut) {
  __shared__ float tile[32][33];
  const float* inm = in + (size_t)blockIdx.z * strideIn;
  bf16* outm = out + (size_t)blockIdx.z * strideOut;
  int tx = threadIdx.x & 31, ty = threadIdx.x >> 5;   // 32 x 8
  int c0 = blockIdx.x * 32, r0 = blockIdx.y * 32;
  #pragma unroll
  for (int j = 0; j < 32; j += 8)
    tile[ty + j][tx] = inm[(size_t)(r0 + ty + j) * C + c0 + tx];
  __syncthreads();
  #pragma unroll
  for (int j = 0; j < 32; j += 8)
    outm[(size_t)(c0 + ty + j) * R + r0 + tx] = (bf16)tile[tx][ty + j];
}

// ---------------- zero small counters
__global__ void init_kernel(int* counts, int* fill) {
  int i = threadIdx.x;
  if (i < NE) { counts[i] = 0; fill[i] = 0; }
}

// ---------------- router: fp64-accumulated logits, softmax, top-4, shared-gate sigmoid
__global__ __launch_bounds__(256) void router_kernel(const float* __restrict__ X,
                                                     const float* __restrict__ Wr,
                                                     const float* __restrict__ wgate,
                                                     float* __restrict__ topk_w,
                                                     int* __restrict__ topk_idx,
                                                     float* __restrict__ gate_sig,
                                                     int* __restrict__ counts) {
  __shared__ float xs[H_DIM];
  __shared__ double lred[NE + 1];
  int t = blockIdx.x, tid = threadIdx.x;
  for (int i = tid; i < H_DIM; i += 256) xs[i] = X[(size_t)t * H_DIM + i];
  __syncthreads();
  int wave = tid >> 6, lane = tid & 63;
  for (int e = wave; e < NE + 1; e += 4) {
    const float* w = (e < NE) ? (Wr + (size_t)e * H_DIM) : wgate;
    double s = 0.0;
    for (int i = lane; i < H_DIM; i += 64) s += (double)xs[i] * (double)w[i];
    #pragma unroll
    for (int off = 32; off; off >>= 1) s += __shfl_xor(s, off);
    if (lane == 0) lred[e] = s;
  }
  __syncthreads();
  if (tid == 0) {
    double lg[NE];
    double m = -1e300;
    for (int e = 0; e < NE; ++e) { lg[e] = lred[e]; if (lg[e] > m) m = lg[e]; }
    double den = 0.0;
    for (int e = 0; e < NE; ++e) den += exp(lg[e] - m);
    bool used[NE] = {};
    for (int k = 0; k < TOPK; ++k) {
      int bi = -1; double bv = -1e300;
      for (int e = 0; e < NE; ++e)
        if (!used[e] && lg[e] > bv) { bv = lg[e]; bi = e; }  // strict > : ties pick lower index
      used[bi] = true;
      topk_idx[t * TOPK + k] = bi;
      topk_w[t * TOPK + k] = (float)(exp(bv - m) / den);
      atomicAdd(&counts[bi], 1);
    }
    gate_sig[t] = (float)(1.0 / (1.0 + exp(-lred[NE])));
  }
}

// ---------------- prefix scan over 16 counts + grouped-GEMM tile table
__global__ void scan_kernel(const int* __restrict__ counts, int* __restrict__ offs,
                            int* __restrict__ fill, int* __restrict__ ttab,
                            int* __restrict__ ntl) {
  if (threadIdx.x != 0) return;
  int off = 0;
  for (int e = 0; e < NE; ++e) { offs[e] = off; off += counts[e]; fill[e] = 0; }
  offs[NE] = off;
  int n = 0;
  for (int e = 0; e < NE; ++e) {
    int cnt = counts[e], end_ = offs[e] + cnt;
    for (int m = 0; m < cnt; m += 128) {
      ttab[n * 3 + 0] = e;
      ttab[n * 3 + 1] = offs[e] + m;
      ttab[n * 3 + 2] = end_;
      ++n;
    }
  }
  *ntl = n;
}

// ---------------- scatter: (t,k) -> sorted position
__global__ __launch_bounds__(256) void scatter_kernel(const int* __restrict__ topk_idx,
                                                      const int* __restrict__ offs,
                                                      int* __restrict__ fill,
                                                      int* __restrict__ row_token,
                                                      int* __restrict__ row_pos) {
  int gid = blockIdx.x * 256 + threadIdx.x;
  if (gid >= TK) return;
  int e = topk_idx[gid];
  int pos = offs[e] + atomicAdd(&fill[e], 1);
  row_token[pos] = gid >> 2;
  row_pos[gid] = pos;
}

// ---------------- generic bf16 MFMA GEMM: C[m][n] = sum_k A[m][k] * B^T[n][k]
// grouped via tile table (nullptr => dense), optional row gather for A.
__global__ __launch_bounds__(256) void gemm_bf16(const bf16* __restrict__ A, int lda,
                                                 const bf16* __restrict__ B, size_t strideB,
                                                 int Ktot,
                                                 bf16* __restrict__ C, int ldc,
                                                 const int* __restrict__ row_token,
                                                 const int* __restrict__ tile_tab,
                                                 const int* __restrict__ n_tiles,
                                                 int Mdense) {
  int mt = blockIdx.x, nt = blockIdx.y;
  int e, row_start, row_end;
  if (tile_tab) {
    if (mt >= *n_tiles) return;
    e = tile_tab[mt * 3 + 0];
    row_start = tile_tab[mt * 3 + 1];
    row_end = tile_tab[mt * 3 + 2];
  } else {
    e = 0; row_start = mt * 128; row_end = Mdense;
  }
  const bf16* Be = B + (size_t)e * strideB;

  __shared__ bf16 As[128][64];
  __shared__ bf16 Bs[128][64];

  const int tid = threadIdx.x;
  const int lane = tid & 63;
  const int wave = tid >> 6;
  const int l8 = lane >> 3;           // 0..7 : row within 8-row staging stripe
  const int kch = (lane & 7) * 8;     // bf16 col offset of this lane's 16B chunk

  // staging source pointers (fixed rows per kt; col advances by 64 per step)
  const bf16* asrc[4];
  const bf16* bsrc[4];
  #pragma unroll
  for (int i = 0; i < 4; ++i) {
    int rloc = wave * 32 + i * 8 + l8;
    int r = row_start + rloc;
    if (r > row_end - 1) r = row_end - 1;           // clamp ragged tail (results discarded)
    int sr = row_token ? row_token[r] : r;
    asrc[i] = A + (size_t)sr * lda + kch;
    bsrc[i] = Be + (size_t)(nt * 128 + rloc) * Ktot + kch;
  }

  f32x4 acc[4][4];
  #pragma unroll
  for (int m = 0; m < 4; ++m)
    #pragma unroll
    for (int n = 0; n < 4; ++n) acc[m][n] = (f32x4){0.f, 0.f, 0.f, 0.f};

  const int wm = (wave >> 1) * 64;    // 2x2 wave grid, each wave owns 64x64
  const int wn = (wave & 1) * 64;
  const int fr = lane & 15;
  const int fk = (lane >> 4) * 8;

  const int nsteps = Ktot >> 6;
  for (int kt = 0; kt < nsteps; ++kt) {
    const size_t ko = (size_t)kt * 64;
    #pragma unroll
    for (int i = 0; i < 4; ++i) {
      gload_lds16(asrc[i] + ko, &As[wave * 32 + i * 8][0]);
      gload_lds16(bsrc[i] + ko, &Bs[wave * 32 + i * 8][0]);
    }
    __syncthreads();
    #pragma unroll
    for (int kk = 0; kk < 2; ++kk) {
      bf16x8 af[4], bv[4];
      #pragma unroll
      for (int m = 0; m < 4; ++m)
        af[m] = *(const bf16x8*)&As[wm + m * 16 + fr][kk * 32 + fk];
      #pragma unroll
      for (int n = 0; n < 4; ++n)
        bv[n] = *(const bf16x8*)&Bs[wn + n * 16 + fr][kk * 32 + fk];
      #pragma unroll
      for (int m = 0; m < 4; ++m)
        #pragma unroll
        for (int n = 0; n < 4; ++n)
          acc[m][n] = __builtin_amdgcn_mfma_f32_16x16x32_bf16(af[m], bv[n], acc[m][n], 0, 0, 0);
    }
    __syncthreads();
  }

  // epilogue: C/D layout col=lane&15, row=(lane>>4)*4+j  (guide §3, m89/m91)
  const int crow0 = row_start + wm + (lane >> 4) * 4;
  const int ccol0 = nt * 128 + wn + fr;
  #pragma unroll
  for (int m = 0; m < 4; ++m)
    #pragma unroll
    for (int n = 0; n < 4; ++n)
      #pragma unroll
      for (int j = 0; j < 4; ++j) {
        int r = crow0 + m * 16 + j;
        if (r < row_end) C[(size_t)r * ldc + ccol0 + n * 16] = (bf16)acc[m][n][j];
      }
}

// ---------------- SwiGLU in place: buf[r][i] = silu(buf[r][i]) * buf[r][i+I]
__global__ __launch_bounds__(256) void swiglu_kernel(bf16* __restrict__ buf, int I, int ld) {
  size_t base = (size_t)blockIdx.x * ld;
  for (int i = threadIdx.x; i < I; i += 256) {
    float g = (float)buf[base + i];
    float u = (float)buf[base + i + I];
    float s = g / (1.f + __expf(-g));
    buf[base + i] = (bf16)(s * u);
  }
}

// ---------------- combine: out[t][h] = sum_k w_tk * eout[pos(t,k)][h] + sig(t)*shared[t][h]
__global__ __launch_bounds__(256) void combine_kernel(const float* __restrict__ topk_w,
                                                      const int* __restrict__ row_pos,
                                                      const bf16* __restrict__ eout,
                                                      const bf16* __restrict__ shout,
                                                      const float* __restrict__ gate_sig,
                                                      float* __restrict__ out) {
  int t = blockIdx.x;
  float w0 = topk_w[t * 4 + 0], w1 = topk_w[t * 4 + 1];
  float w2 = topk_w[t * 4 + 2], w3 = topk_w[t * 4 + 3];
  size_t p0 = (size_t)row_pos[t * 4 + 0] * H_DIM;
  size_t p1 = (size_t)row_pos[t * 4 + 1] * H_DIM;
  size_t p2 = (size_t)row_pos[t * 4 + 2] * H_DIM;
  size_t p3 = (size_t)row_pos[t * 4 + 3] * H_DIM;
  float g = gate_sig[t];
  size_t tb = (size_t)t * H_DIM;
  for (int h = threadIdx.x; h < H_DIM; h += 256) {
    float s = w0 * (float)eout[p0 + h] + w1 * (float)eout[p1 + h]
            + w2 * (float)eout[p2 + h] + w3 * (float)eout[p3 + h]
            + g * (float)shout[tb + h];
    out[tb + h] = s;
  }
}

extern "C" void kernel_launch(void* const* d_in, const int* in_sizes, int n_in,
                              void* d_out, int out_size, void* d_ws, size_t ws_size,
                              hipStream_t stream) {
  const float* X   = (const float*)d_in[0];
  const float* Wr  = (const float*)d_in[1];
  const float* Wgu = (const float*)d_in[2];
  const float* Wd  = (const float*)d_in[3];
  const float* Wsg = (const float*)d_in[4];
  const float* Wsu = (const float*)d_in[5];
  const float* Wsd = (const float*)d_in[6];
  const float* Wge = (const float*)d_in[7];
  float* out = (float*)d_out;

  size_t off = 0;
  auto alloc = [&](size_t bytes) -> void* {
    void* p = (char*)d_ws + off;
    off += (bytes + 255) & ~(size_t)255;
    return p;
  };
  bf16* Xbf    = (bf16*)alloc((size_t)T_TOK * H_DIM * 2);
  bf16* WguT   = (bf16*)alloc((size_t)NE * 2 * IMOE * H_DIM * 2);   // [E][2816][2048]
  bf16* WdT    = (bf16*)alloc((size_t)NE * H_DIM * IMOE * 2);       // [E][2048][1408]
  bf16* WsguT  = (bf16*)alloc((size_t)2 * ISH * H_DIM * 2);         // [11264][2048]
  bf16* WsdT   = (bf16*)alloc((size_t)H_DIM * ISH * 2);             // [2048][5632]
  bf16* merged = (bf16*)alloc((size_t)TK * 2 * IMOE * 2);           // also reused as shared merged
  bf16* eout   = (bf16*)alloc((size_t)TK * H_DIM * 2);
  bf16* shout  = (bf16*)alloc((size_t)T_TOK * H_DIM * 2);
  float* tw    = (float*)alloc((size_t)T_TOK * TOPK * 4);
  int*   tidx  = (int*)alloc((size_t)T_TOK * TOPK * 4);
  float* gsig  = (float*)alloc((size_t)T_TOK * 4);
  int*   counts= (int*)alloc(64);
  int*   offs  = (int*)alloc(128);
  int*   fill  = (int*)alloc(64);
  int*   rowtok= (int*)alloc((size_t)TK * 4);
  int*   rowpos= (int*)alloc((size_t)TK * 4);
  int*   ttab  = (int*)alloc((size_t)MAXTILES * 3 * 4);
  int*   ntl   = (int*)alloc(64);
  if (off > ws_size) return;  // workspace too small -> fail loudly (output stays poisoned)

  init_kernel<<<1, 32, 0, stream>>>(counts, fill);

  // conversions (every call; no cross-call caching allowed)
  cvt_bf16_kernel<<<(T_TOK * H_DIM) / (256 * 8), 256, 0, stream>>>(X, Xbf, (size_t)T_TOK * H_DIM);
  cvt_transpose_kernel<<<dim3(2 * IMOE / 32, H_DIM / 32, NE), 256, 0, stream>>>(
      Wgu, WguT, H_DIM, 2 * IMOE, (size_t)H_DIM * 2 * IMOE, (size_t)H_DIM * 2 * IMOE);
  cvt_transpose_kernel<<<dim3(H_DIM / 32, IMOE / 32, NE), 256, 0, stream>>>(
      Wd, WdT, IMOE, H_DIM, (size_t)IMOE * H_DIM, (size_t)IMOE * H_DIM);
  cvt_transpose_kernel<<<dim3(ISH / 32, H_DIM / 32, 1), 256, 0, stream>>>(
      Wsg, WsguT, H_DIM, ISH, 0, 0);
  cvt_transpose_kernel<<<dim3(ISH / 32, H_DIM / 32, 1), 256, 0, stream>>>(
      Wsu, WsguT + (size_t)ISH * H_DIM, H_DIM, ISH, 0, 0);
  cvt_transpose_kernel<<<dim3(H_DIM / 32, ISH / 32, 1), 256, 0, stream>>>(
      Wsd, WsdT, ISH, H_DIM, 0, 0);

  router_kernel<<<T_TOK, 256, 0, stream>>>(X, Wr, Wge, tw, tidx, gsig, counts);
  scan_kernel<<<1, 64, 0, stream>>>(counts, offs, fill, ttab, ntl);
  scatter_kernel<<<TK / 256, 256, 0, stream>>>(tidx, offs, fill, rowtok, rowpos);

  // grouped GEMM 1: [TK,2048] x [2048,2816] -> merged [TK,2816]
  gemm_bf16<<<dim3(MAXTILES, 2 * IMOE / 128), 256, 0, stream>>>(
      Xbf, H_DIM, WguT, (size_t)2 * IMOE * H_DIM, H_DIM,
      merged, 2 * IMOE, rowtok, ttab, ntl, 0);
  swiglu_kernel<<<TK, 256, 0, stream>>>(merged, IMOE, 2 * IMOE);

  // grouped GEMM 2: act [TK,1408] (lda=2816, in-place swiglu) x [1408,2048] -> eout
  gemm_bf16<<<dim3(MAXTILES, H_DIM / 128), 256, 0, stream>>>(
      merged, 2 * IMOE, WdT, (size_t)H_DIM * IMOE, IMOE,
      eout, H_DIM, nullptr, ttab, ntl, 0);

  // shared expert: dense GEMMs (merged buffer reused, exact same byte size)
  gemm_bf16<<<dim3(T_TOK / 128, 2 * ISH / 128), 256, 0, stream>>>(
      Xbf, H_DIM, WsguT, 0, H_DIM,
      merged, 2 * ISH, nullptr, nullptr, nullptr, T_TOK);
  swiglu_kernel<<<T_TOK, 256, 0, stream>>>(merged, ISH, 2 * ISH);
  gemm_bf16<<<dim3(T_TOK / 128, H_DIM / 128), 256, 0, stream>>>(
      merged, 2 * ISH, WsdT, 0, ISH,
      shout, H_DIM, nullptr, nullptr, nullptr, T_TOK);

  combine_kernel<<<T_TOK, 256, 0, stream>>>(tw, rowpos, eout, shout, gsig, out);
}

// Round 2
// 2208.728 us; speedup vs baseline: 1.2755x; 1.2755x over previous
//
#include <hip/hip_runtime.h>
#include <hip/hip_bf16.h>

#define T_TOK 8192
#define H_DIM 2048
#define NE    16
#define TOPK  4
#define IMOE  1408
#define ISH   5632
#define TK    (T_TOK*TOPK)          // 32768 replicated rows
#define MAXT256 ((TK/256)+NE)       // 144 upper bound on grouped m-tiles (256-row)

typedef __bf16 bf16;
typedef __attribute__((ext_vector_type(8))) __bf16 bf16x8;
typedef __attribute__((ext_vector_type(4))) float  f32x4;

__device__ __forceinline__ void gload_lds16(const bf16* g, bf16* l) {
  __builtin_amdgcn_global_load_lds((const __attribute__((address_space(1))) void*)g,
                                   (__attribute__((address_space(3))) void*)l, 16, 0, 0);
}
#define MEMFENCE asm volatile("" ::: "memory")
#define BARRIER  do { MEMFENCE; __builtin_amdgcn_s_barrier(); MEMFENCE; } while (0)
#define VMCNT4   asm volatile("s_waitcnt vmcnt(4)" ::: "memory")

// ---------------- fp32 -> bf16 straight copy (vectorized, n % 8 == 0)
__global__ __launch_bounds__(256) void cvt_bf16_kernel(const float* __restrict__ in,
                                                       bf16* __restrict__ out, size_t n) {
  size_t i = ((size_t)blockIdx.x * 256 + threadIdx.x) * 8;
  if (i >= n) return;
  float4 v0 = *(const float4*)(in + i);
  float4 v1 = *(const float4*)(in + i + 4);
  bf16x8 o = { (bf16)v0.x,(bf16)v0.y,(bf16)v0.z,(bf16)v0.w,
               (bf16)v1.x,(bf16)v1.y,(bf16)v1.z,(bf16)v1.w };
  *(bf16x8*)(out + i) = o;
}

// ---------------- fp32 [R][C] -> bf16 [C][R] transpose (B^T layout), dims % 32 == 0
__global__ __launch_bounds__(256) void cvt_transpose_kernel(const float* __restrict__ in,
                                                            bf16* __restrict__ out,
                                                            int R, int C,
                                                            size_t strideIn, size_t strideOut) {
  __shared__ float tile[32][33];
  const float* inm = in + (size_t)blockIdx.z * strideIn;
  bf16* outm = out + (size_t)blockIdx.z * strideOut;
  int tx = threadIdx.x & 31, ty = threadIdx.x >> 5;   // 32 x 8
  int c0 = blockIdx.x * 32, r0 = blockIdx.y * 32;
  #pragma unroll
  for (int j = 0; j < 32; j += 8)
    tile[ty + j][tx] = inm[(size_t)(r0 + ty + j) * C + c0 + tx];
  __syncthreads();
  #pragma unroll
  for (int j = 0; j < 32; j += 8)
    outm[(size_t)(c0 + ty + j) * R + r0 + tx] = (bf16)tile[tx][ty + j];
}

// ---------------- zero small counters
__global__ void init_kernel(int* counts, int* fill) {
  int i = threadIdx.x;
  if (i < NE) { counts[i] = 0; fill[i] = 0; }
}

// ---------------- router: fp64-accumulated logits, softmax, top-4, shared-gate sigmoid
__global__ __launch_bounds__(256) void router_kernel(const float* __restrict__ X,
                                                     const float* __restrict__ Wr,
                                                     const float* __restrict__ wgate,
                                                     float* __restrict__ topk_w,
                                                     int* __restrict__ topk_idx,
                                                     float* __restrict__ gate_sig,
                                                     int* __restrict__ counts) {
  __shared__ float xs[H_DIM];
  __shared__ double lred[NE + 1];
  int t = blockIdx.x, tid = threadIdx.x;
  for (int i = tid; i < H_DIM; i += 256) xs[i] = X[(size_t)t * H_DIM + i];
  __syncthreads();
  int wave = tid >> 6, lane = tid & 63;
  for (int e = wave; e < NE + 1; e += 4) {
    const float* w = (e < NE) ? (Wr + (size_t)e * H_DIM) : wgate;
    double s = 0.0;
    for (int i = lane; i < H_DIM; i += 64) s += (double)xs[i] * (double)w[i];
    #pragma unroll
    for (int off = 32; off; off >>= 1) s += __shfl_xor(s, off);
    if (lane == 0) lred[e] = s;
  }
  __syncthreads();
  if (tid == 0) {
    double lg[NE];
    double m = -1e300;
    for (int e = 0; e < NE; ++e) { lg[e] = lred[e]; if (lg[e] > m) m = lg[e]; }
    double den = 0.0;
    for (int e = 0; e < NE; ++e) den += exp(lg[e] - m);
    bool used[NE] = {};
    for (int k = 0; k < TOPK; ++k) {
      int bi = -1; double bv = -1e300;
      for (int e = 0; e < NE; ++e)
        if (!used[e] && lg[e] > bv) { bv = lg[e]; bi = e; }
      used[bi] = true;
      topk_idx[t * TOPK + k] = bi;
      topk_w[t * TOPK + k] = (float)(exp(bv - m) / den);
      atomicAdd(&counts[bi], 1);
    }
    gate_sig[t] = (float)(1.0 / (1.0 + exp(-lred[NE])));
  }
}

// ---------------- prefix scan + 256-row grouped tile table
__global__ void scan_kernel(const int* __restrict__ counts, int* __restrict__ offs,
                            int* __restrict__ fill, int* __restrict__ ttab,
                            int* __restrict__ ntl) {
  if (threadIdx.x != 0) return;
  int off = 0;
  for (int e = 0; e < NE; ++e) { offs[e] = off; off += counts[e]; fill[e] = 0; }
  offs[NE] = off;
  int n = 0;
  for (int e = 0; e < NE; ++e) {
    int cnt = counts[e], end_ = offs[e] + cnt;
    for (int m = 0; m < cnt; m += 256) {
      ttab[n * 3 + 0] = e;
      ttab[n * 3 + 1] = offs[e] + m;
      ttab[n * 3 + 2] = end_;
      ++n;
    }
  }
  *ntl = n;
}

// ---------------- scatter: (t,k) -> sorted position
__global__ __launch_bounds__(256) void scatter_kernel(const int* __restrict__ topk_idx,
                                                      const int* __restrict__ offs,
                                                      int* __restrict__ fill,
                                                      int* __restrict__ row_token,
                                                      int* __restrict__ row_pos) {
  int gid = blockIdx.x * 256 + threadIdx.x;
  if (gid >= TK) return;
  int e = topk_idx[gid];
  int pos = offs[e] + atomicAdd(&fill[e], 1);
  row_token[pos] = gid >> 2;
  row_pos[gid] = pos;
}

// ---------------- 256x256 8-phase bf16 MFMA GEMM: C = A * B^T (B^T rows = out cols)
// grouped via tile table (nullptr => dense), optional row gather for A.
__global__ __launch_bounds__(512, 2) void gemm256(
    const bf16* __restrict__ A, int lda,
    const bf16* __restrict__ B, size_t strideB, int Ktot,
    bf16* __restrict__ C, int ldc,
    const int* __restrict__ row_token,
    const int* __restrict__ tile_tab, const int* __restrict__ n_tiles,
    int Mdense) {
  // T1: bijective XCD swizzle of flattened block id
  unsigned total = gridDim.x * gridDim.y;
  unsigned id = blockIdx.y * gridDim.x + blockIdx.x;
  unsigned qd = total >> 3, rm = total & 7, xc = id & 7, hid = id >> 3;
  unsigned swz = (xc < rm ? xc * (qd + 1) : rm * (qd + 1) + (xc - rm) * qd) + hid;
  int mt = (int)(swz % gridDim.x), nt = (int)(swz / gridDim.x);

  int e, row_start, row_end;
  if (tile_tab) {
    if (mt >= *n_tiles) return;
    e = tile_tab[mt * 3 + 0];
    row_start = tile_tab[mt * 3 + 1];
    row_end = tile_tab[mt * 3 + 2];
  } else {
    e = 0; row_start = mt * 256; row_end = Mdense;
  }
  const bf16* Bp = B + (size_t)e * strideB;

  __shared__ bf16 smA[2][2][8192];   // [buf][half][128*64]
  __shared__ bf16 smB[2][2][8192];

  const int tid = threadIdx.x;
  const int wave = tid >> 6;
  const int lane = tid & 63;

  // staging source element offsets (swizzled global source, rule 21)
  unsigned aoff[2][2], boff[2][2];
  {
    int csrc = (((tid & 7) ^ ((tid >> 3) & 7)) << 3);
    #pragma unroll
    for (int h = 0; h < 2; ++h)
      #pragma unroll
      for (int j = 0; j < 2; ++j) {
        int rho = j * 64 + (tid >> 3);
        int r = row_start + h * 128 + rho;
        if (r > row_end - 1) r = row_end - 1;       // clamp ragged tail
        int sr = row_token ? row_token[r] : r;
        aoff[h][j] = (unsigned)sr * (unsigned)lda + (unsigned)csrc;
        boff[h][j] = (unsigned)(nt * 256 + h * 128 + rho) * (unsigned)Ktot + (unsigned)csrc;
      }
  }

  auto STAGE_A = [&](int bufi, int h, int tt) {
    gload_lds16(A + (size_t)(aoff[h][0] + (unsigned)tt * 64u), &smA[bufi][h][wave << 9]);
    gload_lds16(A + (size_t)(aoff[h][1] + (unsigned)tt * 64u), &smA[bufi][h][4096 + (wave << 9)]);
  };
  auto STAGE_B = [&](int bufi, int h, int tt) {
    gload_lds16(Bp + (size_t)(boff[h][0] + (unsigned)tt * 64u), &smB[bufi][h][wave << 9]);
    gload_lds16(Bp + (size_t)(boff[h][1] + (unsigned)tt * 64u), &smB[bufi][h][4096 + (wave << 9)]);
  };

  const int warow = ((wave >> 2) << 6) + (lane & 15);  // + m*16
  const int wbrow = ((wave & 3) << 5) + (lane & 15);   // + n*16
  const int q4 = lane >> 4;
  auto LDA_ = [&](int bufi, int h, int m, int kk) -> bf16x8 {
    int row = warow + m * 16;
    int c = (kk * 4 + q4) ^ (row & 7);
    return *(const bf16x8*)&smA[bufi][h][row * 64 + c * 8];
  };
  auto LDB_ = [&](int bufi, int h, int n, int kk) -> bf16x8 {
    int row = wbrow + n * 16;
    int c = (kk * 4 + q4) ^ (row & 7);
    return *(const bf16x8*)&smB[bufi][h][row * 64 + c * 8];
  };

  f32x4 acc[4][4][2];   // [quadrant][m][n]
  #pragma unroll
  for (int q = 0; q < 4; ++q)
    #pragma unroll
    for (int m = 0; m < 4; ++m)
      #pragma unroll
      for (int n = 0; n < 2; ++n) acc[q][m][n] = (f32x4){0.f, 0.f, 0.f, 0.f};

  bf16x8 Ar[4][2], Br0[2][2], Br1[2][2];

  // prologue: stage tile 0 into buf 0 (order matches need order: A0,B0,B1,A1)
  STAGE_A(0, 0, 0); STAGE_B(0, 0, 0); STAGE_B(0, 1, 0); STAGE_A(0, 1, 0);

  const int nk = Ktot >> 6;
  for (int t = 0; t < nk; ++t) {
    const int cb = t & 1, nb = cb ^ 1;
    const int ts = (t + 1 < nk) ? (t + 1) : t;  // tail: dummy-stage to keep vmcnt uniform
    // ---- P1: quadrant (A0,B0)
    VMCNT4; BARRIER;
    #pragma unroll
    for (int m = 0; m < 4; ++m)
      #pragma unroll
      for (int kk = 0; kk < 2; ++kk) Ar[m][kk] = LDA_(cb, 0, m, kk);
    #pragma unroll
    for (int n = 0; n < 2; ++n)
      #pragma unroll
      for (int kk = 0; kk < 2; ++kk) Br0[n][kk] = LDB_(cb, 0, n, kk);
    STAGE_A(nb, 0, ts);
    __builtin_amdgcn_s_setprio(1);
    #pragma unroll
    for (int m = 0; m < 4; ++m)
      #pragma unroll
      for (int n = 0; n < 2; ++n)
        #pragma unroll
        for (int kk = 0; kk < 2; ++kk)
          acc[0][m][n] = __builtin_amdgcn_mfma_f32_16x16x32_bf16(Ar[m][kk], Br0[n][kk], acc[0][m][n], 0, 0, 0);
    __builtin_amdgcn_s_setprio(0);
    // ---- P2: quadrant (A0,B1)
    VMCNT4; BARRIER;
    #pragma unroll
    for (int n = 0; n < 2; ++n)
      #pragma unroll
      for (int kk = 0; kk < 2; ++kk) Br1[n][kk] = LDB_(cb, 1, n, kk);
    STAGE_B(nb, 0, ts);
    __builtin_amdgcn_s_setprio(1);
    #pragma unroll
    for (int m = 0; m < 4; ++m)
      #pragma unroll
      for (int n = 0; n < 2; ++n)
        #pragma unroll
        for (int kk = 0; kk < 2; ++kk)
          acc[1][m][n] = __builtin_amdgcn_mfma_f32_16x16x32_bf16(Ar[m][kk], Br1[n][kk], acc[1][m][n], 0, 0, 0);
    __builtin_amdgcn_s_setprio(0);
    // ---- P3: quadrant (A1,B1)
    VMCNT4; BARRIER;
    #pragma unroll
    for (int m = 0; m < 4; ++m)
      #pragma unroll
      for (int kk = 0; kk < 2; ++kk) Ar[m][kk] = LDA_(cb, 1, m, kk);
    STAGE_B(nb, 1, ts);
    __builtin_amdgcn_s_setprio(1);
    #pragma unroll
    for (int m = 0; m < 4; ++m)
      #pragma unroll
      for (int n = 0; n < 2; ++n)
        #pragma unroll
        for (int kk = 0; kk < 2; ++kk)
          acc[2][m][n] = __builtin_amdgcn_mfma_f32_16x16x32_bf16(Ar[m][kk], Br1[n][kk], acc[2][m][n], 0, 0, 0);
    __builtin_amdgcn_s_setprio(0);
    // ---- P4: quadrant (A1,B0) — no new LDS reads, no wait
    STAGE_A(nb, 1, ts);
    __builtin_amdgcn_s_setprio(1);
    #pragma unroll
    for (int m = 0; m < 4; ++m)
      #pragma unroll
      for (int n = 0; n < 2; ++n)
        #pragma unroll
        for (int kk = 0; kk < 2; ++kk)
          acc[3][m][n] = __builtin_amdgcn_mfma_f32_16x16x32_bf16(Ar[m][kk], Br0[n][kk], acc[3][m][n], 0, 0, 0);
    __builtin_amdgcn_s_setprio(0);
  }

  // epilogue: C/D layout col=lane&15, row=(lane>>4)*4+j
  const int qr[4] = {0, 0, 1, 1}, qc[4] = {0, 1, 1, 0};
  const int er = (lane >> 4) * 4;
  #pragma unroll
  for (int q = 0; q < 4; ++q) {
    int rb = row_start + qr[q] * 128 + ((wave >> 2) << 6) + er;
    int cb0 = nt * 256 + qc[q] * 128 + ((wave & 3) << 5) + (lane & 15);
    #pragma unroll
    for (int m = 0; m < 4; ++m)
      #pragma unroll
      for (int n = 0; n < 2; ++n)
        #pragma unroll
        for (int j = 0; j < 4; ++j) {
          int r = rb + m * 16 + j;
          if (r < row_end) C[(size_t)r * ldc + cb0 + n * 16] = (bf16)acc[q][m][n][j];
        }
  }
}

// ---------------- SwiGLU in place, vectorized: buf[r][i] = silu(buf[r][i]) * buf[r][i+I]
__global__ __launch_bounds__(256) void swiglu_kernel(bf16* __restrict__ buf, int I, int ld) {
  size_t base = (size_t)blockIdx.x * ld;
  int vecs = I >> 3;
  for (int v = threadIdx.x; v < vecs; v += 256) {
    bf16x8 g = *(const bf16x8*)&buf[base + (size_t)v * 8];
    bf16x8 u = *(const bf16x8*)&buf[base + I + (size_t)v * 8];
    bf16x8 o;
    #pragma unroll
    for (int j = 0; j < 8; ++j) {
      float gf = (float)g[j];
      float s = gf / (1.f + __expf(-gf));
      o[j] = (bf16)(s * (float)u[j]);
    }
    *(bf16x8*)&buf[base + (size_t)v * 8] = o;
  }
}

// ---------------- combine (vectorized): out = sum_k w*eout[pos] + sig*shared
__global__ __launch_bounds__(256) void combine_kernel(const float* __restrict__ topk_w,
                                                      const int* __restrict__ row_pos,
                                                      const bf16* __restrict__ eout,
                                                      const bf16* __restrict__ shout,
                                                      const float* __restrict__ gate_sig,
                                                      float* __restrict__ out) {
  int t = blockIdx.x;
  float w0 = topk_w[t * 4 + 0], w1 = topk_w[t * 4 + 1];
  float w2 = topk_w[t * 4 + 2], w3 = topk_w[t * 4 + 3];
  size_t p0 = (size_t)row_pos[t * 4 + 0] * H_DIM;
  size_t p1 = (size_t)row_pos[t * 4 + 1] * H_DIM;
  size_t p2 = (size_t)row_pos[t * 4 + 2] * H_DIM;
  size_t p3 = (size_t)row_pos[t * 4 + 3] * H_DIM;
  float g = gate_sig[t];
  size_t tb = (size_t)t * H_DIM;
  size_t hb = (size_t)threadIdx.x * 8;          // 256 threads x 8 = 2048
  bf16x8 a0 = *(const bf16x8*)&eout[p0 + hb];
  bf16x8 a1 = *(const bf16x8*)&eout[p1 + hb];
  bf16x8 a2 = *(const bf16x8*)&eout[p2 + hb];
  bf16x8 a3 = *(const bf16x8*)&eout[p3 + hb];
  bf16x8 sh = *(const bf16x8*)&shout[tb + hb];
  float r[8];
  #pragma unroll
  for (int j = 0; j < 8; ++j)
    r[j] = w0 * (float)a0[j] + w1 * (float)a1[j] + w2 * (float)a2[j]
         + w3 * (float)a3[j] + g * (float)sh[j];
  float4 o0 = {r[0], r[1], r[2], r[3]}, o1 = {r[4], r[5], r[6], r[7]};
  *(float4*)&out[tb + hb] = o0;
  *(float4*)&out[tb + hb + 4] = o1;
}

extern "C" void kernel_launch(void* const* d_in, const int* in_sizes, int n_in,
                              void* d_out, int out_size, void* d_ws, size_t ws_size,
                              hipStream_t stream) {
  const float* X   = (const float*)d_in[0];
  const float* Wr  = (const float*)d_in[1];
  const float* Wgu = (const float*)d_in[2];
  const float* Wd  = (const float*)d_in[3];
  const float* Wsg = (const float*)d_in[4];
  const float* Wsu = (const float*)d_in[5];
  const float* Wsd = (const float*)d_in[6];
  const float* Wge = (const float*)d_in[7];
  float* out = (float*)d_out;

  size_t off = 0;
  auto alloc = [&](size_t bytes) -> void* {
    void* p = (char*)d_ws + off;
    off += (bytes + 255) & ~(size_t)255;
    return p;
  };
  bf16* Xbf    = (bf16*)alloc((size_t)T_TOK * H_DIM * 2);
  bf16* WguT   = (bf16*)alloc((size_t)NE * 2 * IMOE * H_DIM * 2);   // [E][2816][2048]
  bf16* WdT    = (bf16*)alloc((size_t)NE * H_DIM * IMOE * 2);       // [E][2048][1408]
  bf16* WsguT  = (bf16*)alloc((size_t)2 * ISH * H_DIM * 2);         // [11264][2048]
  bf16* WsdT   = (bf16*)alloc((size_t)H_DIM * ISH * 2);             // [2048][5632]
  bf16* merged = (bf16*)alloc((size_t)TK * 2 * IMOE * 2);           // reused as shared merged
  bf16* eout   = (bf16*)alloc((size_t)TK * H_DIM * 2);
  bf16* shout  = (bf16*)alloc((size_t)T_TOK * H_DIM * 2);
  float* tw    = (float*)alloc((size_t)T_TOK * TOPK * 4);
  int*   tidx  = (int*)alloc((size_t)T_TOK * TOPK * 4);
  float* gsig  = (float*)alloc((size_t)T_TOK * 4);
  int*   counts= (int*)alloc(64);
  int*   offs  = (int*)alloc(128);
  int*   fill  = (int*)alloc(64);
  int*   rowtok= (int*)alloc((size_t)TK * 4);
  int*   rowpos= (int*)alloc((size_t)TK * 4);
  int*   ttab  = (int*)alloc((size_t)MAXT256 * 3 * 4);
  int*   ntl   = (int*)alloc(64);
  if (off > ws_size) return;

  init_kernel<<<1, 32, 0, stream>>>(counts, fill);

  cvt_bf16_kernel<<<(T_TOK * H_DIM) / (256 * 8), 256, 0, stream>>>(X, Xbf, (size_t)T_TOK * H_DIM);
  cvt_transpose_kernel<<<dim3(2 * IMOE / 32, H_DIM / 32, NE), 256, 0, stream>>>(
      Wgu, WguT, H_DIM, 2 * IMOE, (size_t)H_DIM * 2 * IMOE, (size_t)H_DIM * 2 * IMOE);
  cvt_transpose_kernel<<<dim3(H_DIM / 32, IMOE / 32, NE), 256, 0, stream>>>(
      Wd, WdT, IMOE, H_DIM, (size_t)IMOE * H_DIM, (size_t)IMOE * H_DIM);
  cvt_transpose_kernel<<<dim3(ISH / 32, H_DIM / 32, 1), 256, 0, stream>>>(
      Wsg, WsguT, H_DIM, ISH, 0, 0);
  cvt_transpose_kernel<<<dim3(ISH / 32, H_DIM / 32, 1), 256, 0, stream>>>(
      Wsu, WsguT + (size_t)ISH * H_DIM, H_DIM, ISH, 0, 0);
  cvt_transpose_kernel<<<dim3(H_DIM / 32, ISH / 32, 1), 256, 0, stream>>>(
      Wsd, WsdT, ISH, H_DIM, 0, 0);

  router_kernel<<<T_TOK, 256, 0, stream>>>(X, Wr, Wge, tw, tidx, gsig, counts);
  scan_kernel<<<1, 64, 0, stream>>>(counts, offs, fill, ttab, ntl);
  scatter_kernel<<<TK / 256, 256, 0, stream>>>(tidx, offs, fill, rowtok, rowpos);

  // grouped GEMM 1: [TK,2048] x [2048,2816] -> merged [TK,2816]
  gemm256<<<dim3(MAXT256, 2 * IMOE / 256), 512, 0, stream>>>(
      Xbf, H_DIM, WguT, (size_t)2 * IMOE * H_DIM, H_DIM,
      merged, 2 * IMOE, rowtok, ttab, ntl, 0);
  swiglu_kernel<<<TK, 256, 0, stream>>>(merged, IMOE, 2 * IMOE);

  // grouped GEMM 2: act [TK,1408] (lda=2816) x [1408,2048] -> eout
  gemm256<<<dim3(MAXT256, H_DIM / 256), 512, 0, stream>>>(
      merged, 2 * IMOE, WdT, (size_t)H_DIM * IMOE, IMOE,
      eout, H_DIM, nullptr, ttab, ntl, 0);

  // shared expert dense GEMMs
  gemm256<<<dim3(T_TOK / 256, 2 * ISH / 256), 512, 0, stream>>>(
      Xbf, H_DIM, WsguT, 0, H_DIM,
      merged, 2 * ISH, nullptr, nullptr, nullptr, T_TOK);
  swiglu_kernel<<<T_TOK, 256, 0, stream>>>(merged, ISH, 2 * ISH);
  gemm256<<<dim3(T_TOK / 256, H_DIM / 256), 512, 0, stream>>>(
      merged, 2 * ISH, WsdT, 0, ISH,
      shout, H_DIM, nullptr, nullptr, nullptr, T_TOK);

  combine_kernel<<<T_TOK, 256, 0, stream>>>(tw, rowpos, eout, shout, gsig, out);
}

// Round 3
// 1937.954 us; speedup vs baseline: 1.4537x; 1.1397x over previous
//
#include <hip/hip_runtime.h>
#include <hip/hip_bf16.h>

#define T_TOK 8192
#define H_DIM 2048
#define NE    16
#define TOPK  4
#define IMOE  1408
#define ISH   5632
#define TK    (T_TOK*TOPK)
#define MAXT256 ((TK/256)+NE)

typedef __bf16 bf16;
typedef __attribute__((ext_vector_type(8))) __bf16 bf16x8;
typedef __attribute__((ext_vector_type(4))) float  f32x4;

__device__ __forceinline__ void gload_lds16(const bf16* g, bf16* l) {
  __builtin_amdgcn_global_load_lds((const __attribute__((address_space(1))) void*)g,
                                   (__attribute__((address_space(3))) void*)l, 16, 0, 0);
}
#define MEMFENCE asm volatile("" ::: "memory")
#define BARRIER  do { MEMFENCE; __builtin_amdgcn_s_barrier(); MEMFENCE; } while (0)
#define VMCNT2   asm volatile("s_waitcnt vmcnt(2)" ::: "memory")
#define VMCNT4   asm volatile("s_waitcnt vmcnt(4)" ::: "memory")

// ---------------- fp32 -> bf16 straight copy
__global__ __launch_bounds__(256) void cvt_bf16_kernel(const float* __restrict__ in,
                                                       bf16* __restrict__ out, size_t n) {
  size_t i = ((size_t)blockIdx.x * 256 + threadIdx.x) * 8;
  if (i >= n) return;
  float4 v0 = *(const float4*)(in + i);
  float4 v1 = *(const float4*)(in + i + 4);
  bf16x8 o = { (bf16)v0.x,(bf16)v0.y,(bf16)v0.z,(bf16)v0.w,
               (bf16)v1.x,(bf16)v1.y,(bf16)v1.z,(bf16)v1.w };
  *(bf16x8*)(out + i) = o;
}

// ---------------- fp32 [R][C] -> bf16 [C'][R] transpose, 64x64 tiles, vectorized.
// Output row remap for swiglu interleave: if split>=0: cl=c(-split if c>=split,
// off+=128); orow=(cl>>7)*256+base_off+off+(cl&127). split<0 => identity.
__global__ __launch_bounds__(256) void cvt_transpose64(const float* __restrict__ in,
                                                       bf16* __restrict__ out,
                                                       int R, int C,
                                                       size_t strideIn, size_t strideOut,
                                                       int split, int base_off) {
  __shared__ float tile[64][65];
  const float* inm = in + (size_t)blockIdx.z * strideIn;
  bf16* outm = out + (size_t)blockIdx.z * strideOut;
  int c0 = blockIdx.x * 64, r0 = blockIdx.y * 64;
  int tid = threadIdx.x;
  int rr = tid >> 4, cc4 = (tid & 15) * 4;
  #pragma unroll
  for (int i = 0; i < 4; ++i) {
    float4 v = *(const float4*)&inm[(size_t)(r0 + rr + i * 16) * C + c0 + cc4];
    tile[rr + i * 16][cc4 + 0] = v.x;
    tile[rr + i * 16][cc4 + 1] = v.y;
    tile[rr + i * 16][cc4 + 2] = v.z;
    tile[rr + i * 16][cc4 + 3] = v.w;
  }
  __syncthreads();
  int r8 = (tid & 7) * 8;
  #pragma unroll
  for (int i = 0; i < 2; ++i) {
    int c = (tid >> 3) + i * 32;
    int co = c0 + c;
    int orow;
    if (split < 0) orow = co;
    else {
      int cl = co, o = base_off;
      if (cl >= split) { cl -= split; o += 128; }
      orow = ((cl >> 7) << 8) + o + (cl & 127);
    }
    bf16x8 v;
    #pragma unroll
    for (int j = 0; j < 8; ++j) v[j] = (bf16)tile[r8 + j][c];
    *(bf16x8*)&outm[(size_t)orow * R + r0 + r8] = v;
  }
}

// ---------------- zero small counters
__global__ void init_kernel(int* counts, int* fill) {
  int i = threadIdx.x;
  if (i < NE) { counts[i] = 0; fill[i] = 0; }
}

// ---------------- router
__global__ __launch_bounds__(256) void router_kernel(const float* __restrict__ X,
                                                     const float* __restrict__ Wr,
                                                     const float* __restrict__ wgate,
                                                     float* __restrict__ topk_w,
                                                     int* __restrict__ topk_idx,
                                                     float* __restrict__ gate_sig,
                                                     int* __restrict__ counts) {
  __shared__ float xs[H_DIM];
  __shared__ double lred[NE + 1];
  int t = blockIdx.x, tid = threadIdx.x;
  for (int i = tid; i < H_DIM; i += 256) xs[i] = X[(size_t)t * H_DIM + i];
  __syncthreads();
  int wave = tid >> 6, lane = tid & 63;
  for (int e = wave; e < NE + 1; e += 4) {
    const float* w = (e < NE) ? (Wr + (size_t)e * H_DIM) : wgate;
    double s = 0.0;
    for (int i = lane; i < H_DIM; i += 64) s += (double)xs[i] * (double)w[i];
    #pragma unroll
    for (int off = 32; off; off >>= 1) s += __shfl_xor(s, off);
    if (lane == 0) lred[e] = s;
  }
  __syncthreads();
  if (tid == 0) {
    double lg[NE];
    double m = -1e300;
    for (int e = 0; e < NE; ++e) { lg[e] = lred[e]; if (lg[e] > m) m = lg[e]; }
    double den = 0.0;
    for (int e = 0; e < NE; ++e) den += exp(lg[e] - m);
    bool used[NE] = {};
    for (int k = 0; k < TOPK; ++k) {
      int bi = -1; double bv = -1e300;
      for (int e = 0; e < NE; ++e)
        if (!used[e] && lg[e] > bv) { bv = lg[e]; bi = e; }
      used[bi] = true;
      topk_idx[t * TOPK + k] = bi;
      topk_w[t * TOPK + k] = (float)(exp(bv - m) / den);
      atomicAdd(&counts[bi], 1);
    }
    gate_sig[t] = (float)(1.0 / (1.0 + exp(-lred[NE])));
  }
}

// ---------------- prefix scan + 256-row grouped tile table
__global__ void scan_kernel(const int* __restrict__ counts, int* __restrict__ offs,
                            int* __restrict__ fill, int* __restrict__ ttab,
                            int* __restrict__ ntl) {
  if (threadIdx.x != 0) return;
  int off = 0;
  for (int e = 0; e < NE; ++e) { offs[e] = off; off += counts[e]; fill[e] = 0; }
  offs[NE] = off;
  int n = 0;
  for (int e = 0; e < NE; ++e) {
    int cnt = counts[e], end_ = offs[e] + cnt;
    for (int m = 0; m < cnt; m += 256) {
      ttab[n * 3 + 0] = e;
      ttab[n * 3 + 1] = offs[e] + m;
      ttab[n * 3 + 2] = end_;
      ++n;
    }
  }
  *ntl = n;
}

// ---------------- scatter
__global__ __launch_bounds__(256) void scatter_kernel(const int* __restrict__ topk_idx,
                                                      const int* __restrict__ offs,
                                                      int* __restrict__ fill,
                                                      int* __restrict__ row_token,
                                                      int* __restrict__ row_pos) {
  int gid = blockIdx.x * 256 + threadIdx.x;
  if (gid >= TK) return;
  int e = topk_idx[gid];
  int pos = offs[e] + atomicAdd(&fill[e], 1);
  row_token[pos] = gid >> 2;
  row_pos[gid] = pos;
}

__device__ __forceinline__ void mfma_cluster(f32x4 (&a)[4][2], bf16x8 (&A)[4][2],
                                             bf16x8 (&B)[2][2]) {
  __builtin_amdgcn_s_setprio(1);
  #pragma unroll
  for (int m = 0; m < 4; ++m)
    #pragma unroll
    for (int n = 0; n < 2; ++n) {
      a[m][n] = __builtin_amdgcn_mfma_f32_16x16x32_bf16(A[m][0], B[n][0], a[m][n], 0, 0, 0);
      a[m][n] = __builtin_amdgcn_mfma_f32_16x16x32_bf16(A[m][1], B[n][1], a[m][n], 0, 0, 0);
    }
  __builtin_amdgcn_s_setprio(0);
}

// ---------------- 256x256 bf16 MFMA GEMM, m201-style phases.
// fuse_swiglu: B cols pre-interleaved [gate128|up128] per 256-tile; epilogue
// writes silu(gate)*up to C (ldc = half width). Else plain bf16 C.
__global__ __launch_bounds__(512, 2) void gemm256(
    const bf16* __restrict__ A, int lda,
    const bf16* __restrict__ B, size_t strideB, int Ktot,
    bf16* __restrict__ C, int ldc,
    const int* __restrict__ row_token,
    const int* __restrict__ tile_tab, const int* __restrict__ n_tiles,
    int Mdense, int fuse_swiglu) {
  unsigned total = gridDim.x * gridDim.y;
  unsigned id = blockIdx.y * gridDim.x + blockIdx.x;
  unsigned qd = total >> 3, rm = total & 7, xc = id & 7, hid = id >> 3;
  unsigned swz = (xc < rm ? xc * (qd + 1) : rm * (qd + 1) + (xc - rm) * qd) + hid;
  int mt = (int)(swz % gridDim.x), nt = (int)(swz / gridDim.x);

  int e, row_start, row_end;
  if (tile_tab) {
    if (mt >= *n_tiles) return;
    e = tile_tab[mt * 3 + 0];
    row_start = tile_tab[mt * 3 + 1];
    row_end = tile_tab[mt * 3 + 2];
  } else {
    e = 0; row_start = mt * 256; row_end = Mdense;
  }
  const bf16* Bp = B + (size_t)e * strideB;

  __shared__ bf16 smA[2][2][8192];   // [buf][half][128*64]
  __shared__ bf16 smB[2][2][8192];

  const int tid = threadIdx.x;
  const int wave = tid >> 6;
  const int lane = tid & 63;

  unsigned aoff[2][2], boff[2][2];
  {
    int csrc = (((tid & 7) ^ ((tid >> 3) & 7)) << 3);
    #pragma unroll
    for (int h = 0; h < 2; ++h)
      #pragma unroll
      for (int j = 0; j < 2; ++j) {
        int rho = j * 64 + (tid >> 3);
        int r = row_start + h * 128 + rho;
        if (r > row_end - 1) r = row_end - 1;
        int sr = row_token ? row_token[r] : r;
        aoff[h][j] = (unsigned)sr * (unsigned)lda + (unsigned)csrc;
        boff[h][j] = (unsigned)(nt * 256 + h * 128 + rho) * (unsigned)Ktot + (unsigned)csrc;
      }
  }

  auto STAGE_A = [&](int bufi, int h, int tt) {
    gload_lds16(A + (size_t)(aoff[h][0] + (unsigned)tt * 64u), &smA[bufi][h][wave << 9]);
    gload_lds16(A + (size_t)(aoff[h][1] + (unsigned)tt * 64u), &smA[bufi][h][4096 + (wave << 9)]);
  };
  auto STAGE_B = [&](int bufi, int h, int tt) {
    gload_lds16(Bp + (size_t)(boff[h][0] + (unsigned)tt * 64u), &smB[bufi][h][wave << 9]);
    gload_lds16(Bp + (size_t)(boff[h][1] + (unsigned)tt * 64u), &smB[bufi][h][4096 + (wave << 9)]);
  };

  const int warow = ((wave >> 2) << 6) + (lane & 15);
  const int wbrow = ((wave & 3) << 5) + (lane & 15);
  const int q4 = lane >> 4;
  auto LDA_ = [&](int bufi, int h, int m, int kk) -> bf16x8 {
    int row = warow + m * 16;
    int c = (kk * 4 + q4) ^ (row & 7);
    return *(const bf16x8*)&smA[bufi][h][row * 64 + c * 8];
  };
  auto LDB_ = [&](int bufi, int h, int n, int kk) -> bf16x8 {
    int row = wbrow + n * 16;
    int c = (kk * 4 + q4) ^ (row & 7);
    return *(const bf16x8*)&smB[bufi][h][row * 64 + c * 8];
  };

  f32x4 acc[4][4][2];
  #pragma unroll
  for (int q = 0; q < 4; ++q)
    #pragma unroll
    for (int m = 0; m < 4; ++m)
      #pragma unroll
      for (int n = 0; n < 2; ++n) acc[q][m][n] = (f32x4){0.f, 0.f, 0.f, 0.f};

  bf16x8 Ar[4][2], Br0[2][2], Br1[2][2];

#define RD_A(BUF, H) do { \
    _Pragma("unroll") for (int m_ = 0; m_ < 4; ++m_) { \
      Ar[m_][0] = LDA_(BUF, H, m_, 0); Ar[m_][1] = LDA_(BUF, H, m_, 1); } } while (0)
#define RD_B(BUF, H, DST) do { \
    _Pragma("unroll") for (int n_ = 0; n_ < 2; ++n_) { \
      DST[n_][0] = LDB_(BUF, H, n_, 0); DST[n_][1] = LDB_(BUF, H, n_, 1); } } while (0)

  // one K-tile: phases {reads | stage-issue | BAR | MFMA | BAR}, vmcnt one phase
  // ahead of the reads it protects (counted, never 0 in steady state).
#define DO_TILE(CB, NB, TS) do { \
    /* f1: q0 = (A0,B0) */ \
    VMCNT2;                       /* covers B1(CB) read at f2 */ \
    RD_A(CB, 0); RD_B(CB, 0, Br0); \
    STAGE_A(NB, 0, TS); \
    BARRIER; \
    mfma_cluster(acc[0], Ar, Br0); \
    BARRIER; \
    /* f2: q1 = (A0,B1) */ \
    VMCNT2;                       /* covers A1(CB) read at f3 */ \
    RD_B(CB, 1, Br1); \
    STAGE_B(NB, 0, TS); \
    BARRIER; \
    mfma_cluster(acc[1], Ar, Br1); \
    BARRIER; \
    /* f3: q2 = (A1,B1) */ \
    RD_A(CB, 1); \
    STAGE_B(NB, 1, TS); \
    BARRIER; \
    mfma_cluster(acc[2], Ar, Br1); \
    BARRIER; \
    /* f4: q3 = (A1,B0) */ \
    VMCNT2;                       /* covers A0,B0(NB) read at next f1 */ \
    STAGE_A(NB, 1, TS); \
    mfma_cluster(acc[3], Ar, Br0); \
    BARRIER; \
  } while (0)

  // prologue: stage tile 0, guarantee A0,B0 landed for f1 reads
  STAGE_A(0, 0, 0); STAGE_B(0, 0, 0); STAGE_B(0, 1, 0); STAGE_A(0, 1, 0);
  VMCNT4; BARRIER;

  const int nk = Ktot >> 6;            // even for all shapes used here
  for (int it = 0; it < nk; it += 2) {
    const int ts1 = it + 1;
    const int ts2 = (it + 2 < nk) ? it + 2 : it + 1;  // tail: dummy re-stage
    DO_TILE(0, 1, ts1);
    DO_TILE(1, 0, ts2);
  }
#undef DO_TILE
#undef RD_A
#undef RD_B

  const int er = (lane >> 4) * 4;
  if (fuse_swiglu) {
    // quadrant pairs: (q0 gate, q1 up) rows A0; (q3 gate, q2 up) rows A1.
    const int cb0 = nt * 128 + ((wave & 3) << 5) + (lane & 15);
    #pragma unroll
    for (int qi = 0; qi < 2; ++qi) {
      const int qg = qi ? 3 : 0, qu = qi ? 2 : 1;
      int rb = row_start + qi * 128 + ((wave >> 2) << 6) + er;
      #pragma unroll
      for (int m = 0; m < 4; ++m)
        #pragma unroll
        for (int n = 0; n < 2; ++n)
          #pragma unroll
          for (int j = 0; j < 4; ++j) {
            int r = rb + m * 16 + j;
            if (r < row_end) {
              float g = acc[qg][m][n][j];
              float u = acc[qu][m][n][j];
              float s = g / (1.f + __expf(-g));
              C[(size_t)r * ldc + cb0 + n * 16] = (bf16)(s * u);
            }
          }
    }
  } else {
    const int qr[4] = {0, 0, 1, 1}, qc[4] = {0, 1, 1, 0};
    #pragma unroll
    for (int q = 0; q < 4; ++q) {
      int rb = row_start + qr[q] * 128 + ((wave >> 2) << 6) + er;
      int cb0 = nt * 256 + qc[q] * 128 + ((wave & 3) << 5) + (lane & 15);
      #pragma unroll
      for (int m = 0; m < 4; ++m)
        #pragma unroll
        for (int n = 0; n < 2; ++n)
          #pragma unroll
          for (int j = 0; j < 4; ++j) {
            int r = rb + m * 16 + j;
            if (r < row_end) C[(size_t)r * ldc + cb0 + n * 16] = (bf16)acc[q][m][n][j];
          }
    }
  }
}

// ---------------- combine
__global__ __launch_bounds__(256) void combine_kernel(const float* __restrict__ topk_w,
                                                      const int* __restrict__ row_pos,
                                                      const bf16* __restrict__ eout,
                                                      const bf16* __restrict__ shout,
                                                      const float* __restrict__ gate_sig,
                                                      float* __restrict__ out) {
  int t = blockIdx.x;
  float w0 = topk_w[t * 4 + 0], w1 = topk_w[t * 4 + 1];
  float w2 = topk_w[t * 4 + 2], w3 = topk_w[t * 4 + 3];
  size_t p0 = (size_t)row_pos[t * 4 + 0] * H_DIM;
  size_t p1 = (size_t)row_pos[t * 4 + 1] * H_DIM;
  size_t p2 = (size_t)row_pos[t * 4 + 2] * H_DIM;
  size_t p3 = (size_t)row_pos[t * 4 + 3] * H_DIM;
  float g = gate_sig[t];
  size_t tb = (size_t)t * H_DIM;
  size_t hb = (size_t)threadIdx.x * 8;
  bf16x8 a0 = *(const bf16x8*)&eout[p0 + hb];
  bf16x8 a1 = *(const bf16x8*)&eout[p1 + hb];
  bf16x8 a2 = *(const bf16x8*)&eout[p2 + hb];
  bf16x8 a3 = *(const bf16x8*)&eout[p3 + hb];
  bf16x8 sh = *(const bf16x8*)&shout[tb + hb];
  float r[8];
  #pragma unroll
  for (int j = 0; j < 8; ++j)
    r[j] = w0 * (float)a0[j] + w1 * (float)a1[j] + w2 * (float)a2[j]
         + w3 * (float)a3[j] + g * (float)sh[j];
  float4 o0 = {r[0], r[1], r[2], r[3]}, o1 = {r[4], r[5], r[6], r[7]};
  *(float4*)&out[tb + hb] = o0;
  *(float4*)&out[tb + hb + 4] = o1;
}

extern "C" void kernel_launch(void* const* d_in, const int* in_sizes, int n_in,
                              void* d_out, int out_size, void* d_ws, size_t ws_size,
                              hipStream_t stream) {
  const float* X   = (const float*)d_in[0];
  const float* Wr  = (const float*)d_in[1];
  const float* Wgu = (const float*)d_in[2];
  const float* Wd  = (const float*)d_in[3];
  const float* Wsg = (const float*)d_in[4];
  const float* Wsu = (const float*)d_in[5];
  const float* Wsd = (const float*)d_in[6];
  const float* Wge = (const float*)d_in[7];
  float* out = (float*)d_out;

  size_t off = 0;
  auto alloc = [&](size_t bytes) -> void* {
    void* p = (char*)d_ws + off;
    off += (bytes + 255) & ~(size_t)255;
    return p;
  };
  bf16* Xbf    = (bf16*)alloc((size_t)T_TOK * H_DIM * 2);
  bf16* WguT   = (bf16*)alloc((size_t)NE * 2 * IMOE * H_DIM * 2);   // interleaved [E][2816][2048]
  bf16* WdT    = (bf16*)alloc((size_t)NE * H_DIM * IMOE * 2);       // [E][2048][1408]
  bf16* WsguT  = (bf16*)alloc((size_t)2 * ISH * H_DIM * 2);         // interleaved [11264][2048]
  bf16* WsdT   = (bf16*)alloc((size_t)H_DIM * ISH * 2);             // [2048][5632]
  bf16* act    = (bf16*)alloc((size_t)TK * IMOE * 2);               // fused swiglu out
  bf16* act_sh = (bf16*)alloc((size_t)T_TOK * ISH * 2);
  bf16* eout   = (bf16*)alloc((size_t)TK * H_DIM * 2);
  bf16* shout  = (bf16*)alloc((size_t)T_TOK * H_DIM * 2);
  float* tw    = (float*)alloc((size_t)T_TOK * TOPK * 4);
  int*   tidx  = (int*)alloc((size_t)T_TOK * TOPK * 4);
  float* gsig  = (float*)alloc((size_t)T_TOK * 4);
  int*   counts= (int*)alloc(64);
  int*   offs  = (int*)alloc(128);
  int*   fill  = (int*)alloc(64);
  int*   rowtok= (int*)alloc((size_t)TK * 4);
  int*   rowpos= (int*)alloc((size_t)TK * 4);
  int*   ttab  = (int*)alloc((size_t)MAXT256 * 3 * 4);
  int*   ntl   = (int*)alloc(64);
  if (off > ws_size) return;

  init_kernel<<<1, 32, 0, stream>>>(counts, fill);

  cvt_bf16_kernel<<<(T_TOK * H_DIM) / (256 * 8), 256, 0, stream>>>(X, Xbf, (size_t)T_TOK * H_DIM);
  // Wgu: interleave gate/up columns per 128-block (split at IMOE)
  cvt_transpose64<<<dim3(2 * IMOE / 64, H_DIM / 64, NE), 256, 0, stream>>>(
      Wgu, WguT, H_DIM, 2 * IMOE, (size_t)H_DIM * 2 * IMOE, (size_t)H_DIM * 2 * IMOE, IMOE, 0);
  cvt_transpose64<<<dim3(H_DIM / 64, IMOE / 64, NE), 256, 0, stream>>>(
      Wd, WdT, IMOE, H_DIM, (size_t)IMOE * H_DIM, (size_t)IMOE * H_DIM, -1, 0);
  // shared gate/up: interleave across the two tensors
  cvt_transpose64<<<dim3(ISH / 64, H_DIM / 64, 1), 256, 0, stream>>>(
      Wsg, WsguT, H_DIM, ISH, 0, 0, ISH, 0);
  cvt_transpose64<<<dim3(ISH / 64, H_DIM / 64, 1), 256, 0, stream>>>(
      Wsu, WsguT, H_DIM, ISH, 0, 0, ISH, 128);
  cvt_transpose64<<<dim3(H_DIM / 64, ISH / 64, 1), 256, 0, stream>>>(
      Wsd, WsdT, ISH, H_DIM, 0, 0, -1, 0);

  router_kernel<<<T_TOK, 256, 0, stream>>>(X, Wr, Wge, tw, tidx, gsig, counts);
  scan_kernel<<<1, 64, 0, stream>>>(counts, offs, fill, ttab, ntl);
  scatter_kernel<<<TK / 256, 256, 0, stream>>>(tidx, offs, fill, rowtok, rowpos);

  // grouped GEMM 1 + fused swiglu: [TK,2048] x [2048,2816] -> act [TK,1408]
  gemm256<<<dim3(MAXT256, 2 * IMOE / 256), 512, 0, stream>>>(
      Xbf, H_DIM, WguT, (size_t)2 * IMOE * H_DIM, H_DIM,
      act, IMOE, rowtok, ttab, ntl, 0, 1);

  // grouped GEMM 2: act [TK,1408] x [1408,2048] -> eout
  gemm256<<<dim3(MAXT256, H_DIM / 256), 512, 0, stream>>>(
      act, IMOE, WdT, (size_t)H_DIM * IMOE, IMOE,
      eout, H_DIM, nullptr, ttab, ntl, 0, 0);

  // shared expert: dense gate_up + fused swiglu -> act_sh [8192,5632]
  gemm256<<<dim3(T_TOK / 256, 2 * ISH / 256), 512, 0, stream>>>(
      Xbf, H_DIM, WsguT, 0, H_DIM,
      act_sh, ISH, nullptr, nullptr, nullptr, T_TOK, 1);
  gemm256<<<dim3(T_TOK / 256, H_DIM / 256), 512, 0, stream>>>(
      act_sh, ISH, WsdT, 0, ISH,
      shout, H_DIM, nullptr, nullptr, nullptr, T_TOK, 0);

  combine_kernel<<<T_TOK, 256, 0, stream>>>(tw, rowpos, eout, shout, gsig, out);
}

// Round 4
// 1484.561 us; speedup vs baseline: 1.8977x; 1.3054x over previous
//
#include <hip/hip_runtime.h>
#include <hip/hip_bf16.h>

#define T_TOK 8192
#define H_DIM 2048
#define NE    16
#define TOPK  4
#define IMOE  1408
#define ISH   5632
#define TK    (T_TOK*TOPK)
#define MAXT256 ((TK/256)+NE)

typedef __bf16 bf16;
typedef __attribute__((ext_vector_type(8))) __bf16 bf16x8;
typedef __attribute__((ext_vector_type(4))) float  f32x4;

__device__ __forceinline__ void gload_lds16(const bf16* g, bf16* l) {
  __builtin_amdgcn_global_load_lds((const __attribute__((address_space(1))) void*)g,
                                   (__attribute__((address_space(3))) void*)l, 16, 0, 0);
}
#define MEMFENCE asm volatile("" ::: "memory")
#define BARRIER  do { MEMFENCE; __builtin_amdgcn_s_barrier(); MEMFENCE; } while (0)
#define VMCNT4   asm volatile("s_waitcnt vmcnt(4)" ::: "memory")

// ---------------- fp32 [R][C] -> bf16 [C'][R] transpose, 64x64 tiles, vectorized.
__global__ __launch_bounds__(256) void cvt_transpose64(const float* __restrict__ in,
                                                       bf16* __restrict__ out,
                                                       int R, int C,
                                                       size_t strideIn, size_t strideOut,
                                                       int split, int base_off) {
  __shared__ float tile[64][65];
  const float* inm = in + (size_t)blockIdx.z * strideIn;
  bf16* outm = out + (size_t)blockIdx.z * strideOut;
  int c0 = blockIdx.x * 64, r0 = blockIdx.y * 64;
  int tid = threadIdx.x;
  int rr = tid >> 4, cc4 = (tid & 15) * 4;
  #pragma unroll
  for (int i = 0; i < 4; ++i) {
    float4 v = *(const float4*)&inm[(size_t)(r0 + rr + i * 16) * C + c0 + cc4];
    tile[rr + i * 16][cc4 + 0] = v.x;
    tile[rr + i * 16][cc4 + 1] = v.y;
    tile[rr + i * 16][cc4 + 2] = v.z;
    tile[rr + i * 16][cc4 + 3] = v.w;
  }
  __syncthreads();
  int r8 = (tid & 7) * 8;
  #pragma unroll
  for (int i = 0; i < 2; ++i) {
    int c = (tid >> 3) + i * 32;
    int co = c0 + c;
    int orow;
    if (split < 0) orow = co;
    else {
      int cl = co, o = base_off;
      if (cl >= split) { cl -= split; o += 128; }
      orow = ((cl >> 7) << 8) + o + (cl & 127);
    }
    bf16x8 v;
    #pragma unroll
    for (int j = 0; j < 8; ++j) v[j] = (bf16)tile[r8 + j][c];
    *(bf16x8*)&outm[(size_t)orow * R + r0 + r8] = v;
  }
}

// ---------------- zero small counters
__global__ void init_kernel(int* counts, int* fill) {
  int i = threadIdx.x;
  if (i < NE) { counts[i] = 0; fill[i] = 0; }
}

// ---------------- router: wave-per-token, fp64-accumulated logits, lane-parallel
// softmax/top-4, no atomics. Also emits Xbf (bf16 copy of X).
__global__ __launch_bounds__(256) void router_kernel(const float* __restrict__ X,
                                                     const float* __restrict__ Wr,
                                                     const float* __restrict__ wgate,
                                                     bf16* __restrict__ Xbf,
                                                     float* __restrict__ topk_w,
                                                     int* __restrict__ topk_idx,
                                                     float* __restrict__ gate_sig) {
  const int wv = threadIdx.x >> 6, lane = threadIdx.x & 63;
  const int t = blockIdx.x * 4 + wv;
  const float* x = X + (size_t)t * H_DIM;
  float xf[32];
  #pragma unroll
  for (int j = 0; j < 32; ++j) xf[j] = x[j * 64 + lane];
  #pragma unroll
  for (int j = 0; j < 32; ++j) Xbf[(size_t)t * H_DIM + j * 64 + lane] = (bf16)xf[j];

  double lg = 0.0;   // lane e holds logit e (e<16); lane 16 holds shared-gate logit
  for (int e = 0; e < NE + 1; ++e) {
    const float* w = (e < NE) ? (Wr + (size_t)e * H_DIM) : wgate;
    double s0 = 0.0, s1 = 0.0;
    #pragma unroll
    for (int j = 0; j < 32; j += 2) {
      s0 += (double)xf[j] * (double)w[j * 64 + lane];
      s1 += (double)xf[j + 1] * (double)w[(j + 1) * 64 + lane];
    }
    double s = s0 + s1;
    #pragma unroll
    for (int off = 32; off; off >>= 1) s += __shfl_xor(s, off);
    if (lane == e) lg = s;
  }

  double v = (lane < NE) ? lg : -1e300;
  double m = v;
  #pragma unroll
  for (int off = 32; off; off >>= 1) m = fmax(m, __shfl_xor(m, off));
  double ev = (lane < NE) ? exp(v - m) : 0.0;
  double den = ev;
  #pragma unroll
  for (int off = 32; off; off >>= 1) den += __shfl_xor(den, off);

  double vv = v;
  int widx = 0; double wval = 0.0;
  for (int k = 0; k < TOPK; ++k) {
    double bv = vv; int bi = lane;
    #pragma unroll
    for (int off = 32; off; off >>= 1) {
      double ov = __shfl_xor(bv, off);
      int oi = __shfl_xor(bi, off);
      if (ov > bv || (ov == bv && oi < bi)) { bv = ov; bi = oi; }
    }
    double evb = __shfl(ev, bi);
    if (lane == k) { widx = bi; wval = evb / den; }
    if (lane == bi) vv = -1e300;
  }
  if (lane < TOPK) {
    topk_idx[t * TOPK + lane] = widx;
    topk_w[t * TOPK + lane] = (float)wval;
  }
  if (lane == NE) gate_sig[t] = (float)(1.0 / (1.0 + exp(-lg)));
}

// ---------------- histogram of expert assignments (LDS-local, 16 atomics/block)
__global__ __launch_bounds__(256) void hist_kernel(const int* __restrict__ tidx,
                                                   int* __restrict__ counts) {
  __shared__ int h[NE];
  if (threadIdx.x < NE) h[threadIdx.x] = 0;
  __syncthreads();
  int gid = blockIdx.x * 256 + threadIdx.x;
  atomicAdd(&h[tidx[gid]], 1);
  __syncthreads();
  if (threadIdx.x < NE) atomicAdd(&counts[threadIdx.x], h[threadIdx.x]);
}

// ---------------- prefix scan + 256-row grouped tile table
__global__ void scan_kernel(const int* __restrict__ counts, int* __restrict__ offs,
                            int* __restrict__ fill, int* __restrict__ ttab,
                            int* __restrict__ ntl) {
  if (threadIdx.x != 0) return;
  int off = 0;
  for (int e = 0; e < NE; ++e) { offs[e] = off; off += counts[e]; fill[e] = 0; }
  offs[NE] = off;
  int n = 0;
  for (int e = 0; e < NE; ++e) {
    int cnt = counts[e], end_ = offs[e] + cnt;
    for (int m = 0; m < cnt; m += 256) {
      ttab[n * 3 + 0] = e;
      ttab[n * 3 + 1] = offs[e] + m;
      ttab[n * 3 + 2] = end_;
      ++n;
    }
  }
  *ntl = n;
}

// ---------------- scatter: hierarchical rank (ballot) + 16 atomics/block
__global__ __launch_bounds__(256) void scatter_kernel(const int* __restrict__ topk_idx,
                                                      const int* __restrict__ offs,
                                                      int* __restrict__ fill,
                                                      int* __restrict__ row_token,
                                                      int* __restrict__ row_pos) {
  __shared__ int wc[4][NE];
  __shared__ int wbase[4][NE];
  __shared__ int bbase[NE];
  const int tid = threadIdx.x, wv = tid >> 6, lane = tid & 63;
  const int gid = blockIdx.x * 256 + tid;
  const int e = topk_idx[gid];
  int rank = 0;
  #pragma unroll
  for (int ex = 0; ex < NE; ++ex) {
    unsigned long long b = __ballot(e == ex);
    if (e == ex) rank = __popcll(b & ((1ull << lane) - 1));
    if (lane == 0) wc[wv][ex] = __popcll(b);
  }
  __syncthreads();
  if (tid < NE) {
    int s = 0;
    #pragma unroll
    for (int w = 0; w < 4; ++w) { wbase[w][tid] = s; s += wc[w][tid]; }
    bbase[tid] = atomicAdd(&fill[tid], s);
  }
  __syncthreads();
  int pos = offs[e] + bbase[e] + wbase[wv][e] + rank;
  row_token[pos] = gid >> 2;
  row_pos[gid] = pos;
}

__device__ __forceinline__ void mfma_cluster(f32x4 (&a)[4][2], bf16x8 (&A)[4][2],
                                             bf16x8 (&B)[2][2]) {
  __builtin_amdgcn_s_setprio(1);
  #pragma unroll
  for (int m = 0; m < 4; ++m)
    #pragma unroll
    for (int n = 0; n < 2; ++n) {
      a[m][n] = __builtin_amdgcn_mfma_f32_16x16x32_bf16(A[m][0], B[n][0], a[m][n], 0, 0, 0);
      a[m][n] = __builtin_amdgcn_mfma_f32_16x16x32_bf16(A[m][1], B[n][1], a[m][n], 0, 0, 0);
    }
  __builtin_amdgcn_s_setprio(0);
}

// ---------------- 256x256 bf16 MFMA GEMM, m201-style phases, safe counted vmcnt.
__global__ __launch_bounds__(512, 2) void gemm256(
    const bf16* __restrict__ A, int lda,
    const bf16* __restrict__ B, size_t strideB, int Ktot,
    bf16* __restrict__ C, int ldc,
    const int* __restrict__ row_token,
    const int* __restrict__ tile_tab, const int* __restrict__ n_tiles,
    int Mdense, int fuse_swiglu) {
  unsigned total = gridDim.x * gridDim.y;
  unsigned id = blockIdx.y * gridDim.x + blockIdx.x;
  unsigned qd = total >> 3, rm = total & 7, xc = id & 7, hid = id >> 3;
  unsigned swz = (xc < rm ? xc * (qd + 1) : rm * (qd + 1) + (xc - rm) * qd) + hid;
  int mt = (int)(swz % gridDim.x), nt = (int)(swz / gridDim.x);

  int e, row_start, row_end;
  if (tile_tab) {
    if (mt >= *n_tiles) return;
    e = tile_tab[mt * 3 + 0];
    row_start = tile_tab[mt * 3 + 1];
    row_end = tile_tab[mt * 3 + 2];
  } else {
    e = 0; row_start = mt * 256; row_end = Mdense;
  }
  const bf16* Bp = B + (size_t)e * strideB;

  __shared__ bf16 smA[2][2][8192];   // [buf][half][128*64]
  __shared__ bf16 smB[2][2][8192];

  const int tid = threadIdx.x;
  const int wave = tid >> 6;
  const int lane = tid & 63;

  unsigned aoff[2][2], boff[2][2];
  {
    int csrc = (((tid & 7) ^ ((tid >> 3) & 7)) << 3);
    #pragma unroll
    for (int h = 0; h < 2; ++h)
      #pragma unroll
      for (int j = 0; j < 2; ++j) {
        int rho = j * 64 + (tid >> 3);
        int r = row_start + h * 128 + rho;
        if (r > row_end - 1) r = row_end - 1;
        int sr = row_token ? row_token[r] : r;
        aoff[h][j] = (unsigned)sr * (unsigned)lda + (unsigned)csrc;
        boff[h][j] = (unsigned)(nt * 256 + h * 128 + rho) * (unsigned)Ktot + (unsigned)csrc;
      }
  }

  auto STAGE_A = [&](int bufi, int h, int tt) {
    gload_lds16(A + (size_t)(aoff[h][0] + (unsigned)tt * 64u), &smA[bufi][h][wave << 9]);
    gload_lds16(A + (size_t)(aoff[h][1] + (unsigned)tt * 64u), &smA[bufi][h][4096 + (wave << 9)]);
  };
  auto STAGE_B = [&](int bufi, int h, int tt) {
    gload_lds16(Bp + (size_t)(boff[h][0] + (unsigned)tt * 64u), &smB[bufi][h][wave << 9]);
    gload_lds16(Bp + (size_t)(boff[h][1] + (unsigned)tt * 64u), &smB[bufi][h][4096 + (wave << 9)]);
  };

  const int warow = ((wave >> 2) << 6) + (lane & 15);
  const int wbrow = ((wave & 3) << 5) + (lane & 15);
  const int q4 = lane >> 4;
  auto LDA_ = [&](int bufi, int h, int m, int kk) -> bf16x8 {
    int row = warow + m * 16;
    int c = (kk * 4 + q4) ^ (row & 7);
    return *(const bf16x8*)&smA[bufi][h][row * 64 + c * 8];
  };
  auto LDB_ = [&](int bufi, int h, int n, int kk) -> bf16x8 {
    int row = wbrow + n * 16;
    int c = (kk * 4 + q4) ^ (row & 7);
    return *(const bf16x8*)&smB[bufi][h][row * 64 + c * 8];
  };

  f32x4 acc[4][4][2];
  #pragma unroll
  for (int q = 0; q < 4; ++q)
    #pragma unroll
    for (int m = 0; m < 4; ++m)
      #pragma unroll
      for (int n = 0; n < 2; ++n) acc[q][m][n] = (f32x4){0.f, 0.f, 0.f, 0.f};

  bf16x8 Ar[4][2], Br0[2][2], Br1[2][2];

#define RD_A(BUF, H) do { \
    _Pragma("unroll") for (int m_ = 0; m_ < 4; ++m_) { \
      Ar[m_][0] = LDA_(BUF, H, m_, 0); Ar[m_][1] = LDA_(BUF, H, m_, 1); } } while (0)
#define RD_B(BUF, H, DST) do { \
    _Pragma("unroll") for (int n_ = 0; n_ < 2; ++n_) { \
      DST[n_][0] = LDB_(BUF, H, n_, 0); DST[n_][1] = LDB_(BUF, H, n_, 1); } } while (0)

  // Safe counted-vmcnt schedule: each vmcnt(4) sits BEFORE the barrier that
  // separates it from the cross-wave reads it protects (stager wait -> barrier
  // -> read). Steady state keeps 4-6 loads in flight, never drains to 0.
#define DO_TILE(CB, NB, TS) do { \
    /* f1: q0 = (A0,B0); protects B1(CB) for f2 */ \
    RD_A(CB, 0); RD_B(CB, 0, Br0); \
    STAGE_A(NB, 0, TS); \
    VMCNT4; BARRIER; \
    mfma_cluster(acc[0], Ar, Br0); \
    BARRIER; \
    /* f2: q1 = (A0,B1); protects A1(CB) for f3 */ \
    RD_B(CB, 1, Br1); \
    STAGE_B(NB, 0, TS); \
    VMCNT4; BARRIER; \
    mfma_cluster(acc[1], Ar, Br1); \
    BARRIER; \
    /* f3: q2 = (A1,B1) */ \
    RD_A(CB, 1); \
    STAGE_B(NB, 1, TS); \
    BARRIER; \
    mfma_cluster(acc[2], Ar, Br1); \
    BARRIER; \
    /* f4: q3 = (A1,B0); protects A0,B0(NB) for next f1 */ \
    STAGE_A(NB, 1, TS); \
    VMCNT4; \
    mfma_cluster(acc[3], Ar, Br0); \
    BARRIER; \
  } while (0)

  STAGE_A(0, 0, 0); STAGE_B(0, 0, 0); STAGE_B(0, 1, 0); STAGE_A(0, 1, 0);
  VMCNT4; BARRIER;

  const int nk = Ktot >> 6;
  for (int it = 0; it < nk; it += 2) {
    const int ts1 = it + 1;
    const int ts2 = (it + 2 < nk) ? it + 2 : it + 1;
    DO_TILE(0, 1, ts1);
    DO_TILE(1, 0, ts2);
  }
#undef DO_TILE
#undef RD_A
#undef RD_B

  const int er = (lane >> 4) * 4;
  if (fuse_swiglu) {
    const int cb0 = nt * 128 + ((wave & 3) << 5) + (lane & 15);
    #pragma unroll
    for (int qi = 0; qi < 2; ++qi) {
      const int qg = qi ? 3 : 0, qu = qi ? 2 : 1;
      int rb = row_start + qi * 128 + ((wave >> 2) << 6) + er;
      #pragma unroll
      for (int m = 0; m < 4; ++m)
        #pragma unroll
        for (int n = 0; n < 2; ++n)
          #pragma unroll
          for (int j = 0; j < 4; ++j) {
            int r = rb + m * 16 + j;
            if (r < row_end) {
              float g = acc[qg][m][n][j];
              float u = acc[qu][m][n][j];
              float s = g / (1.f + __expf(-g));
              C[(size_t)r * ldc + cb0 + n * 16] = (bf16)(s * u);
            }
          }
    }
  } else {
    const int qr[4] = {0, 0, 1, 1}, qc[4] = {0, 1, 1, 0};
    #pragma unroll
    for (int q = 0; q < 4; ++q) {
      int rb = row_start + qr[q] * 128 + ((wave >> 2) << 6) + er;
      int cb0 = nt * 256 + qc[q] * 128 + ((wave & 3) << 5) + (lane & 15);
      #pragma unroll
      for (int m = 0; m < 4; ++m)
        #pragma unroll
        for (int n = 0; n < 2; ++n)
          #pragma unroll
          for (int j = 0; j < 4; ++j) {
            int r = rb + m * 16 + j;
            if (r < row_end) C[(size_t)r * ldc + cb0 + n * 16] = (bf16)acc[q][m][n][j];
          }
    }
  }
}

// ---------------- combine
__global__ __launch_bounds__(256) void combine_kernel(const float* __restrict__ topk_w,
                                                      const int* __restrict__ row_pos,
                                                      const bf16* __restrict__ eout,
                                                      const bf16* __restrict__ shout,
                                                      const float* __restrict__ gate_sig,
                                                      float* __restrict__ out) {
  int t = blockIdx.x;
  float w0 = topk_w[t * 4 + 0], w1 = topk_w[t * 4 + 1];
  float w2 = topk_w[t * 4 + 2], w3 = topk_w[t * 4 + 3];
  size_t p0 = (size_t)row_pos[t * 4 + 0] * H_DIM;
  size_t p1 = (size_t)row_pos[t * 4 + 1] * H_DIM;
  size_t p2 = (size_t)row_pos[t * 4 + 2] * H_DIM;
  size_t p3 = (size_t)row_pos[t * 4 + 3] * H_DIM;
  float g = gate_sig[t];
  size_t tb = (size_t)t * H_DIM;
  size_t hb = (size_t)threadIdx.x * 8;
  bf16x8 a0 = *(const bf16x8*)&eout[p0 + hb];
  bf16x8 a1 = *(const bf16x8*)&eout[p1 + hb];
  bf16x8 a2 = *(const bf16x8*)&eout[p2 + hb];
  bf16x8 a3 = *(const bf16x8*)&eout[p3 + hb];
  bf16x8 sh = *(const bf16x8*)&shout[tb + hb];
  float r[8];
  #pragma unroll
  for (int j = 0; j < 8; ++j)
    r[j] = w0 * (float)a0[j] + w1 * (float)a1[j] + w2 * (float)a2[j]
         + w3 * (float)a3[j] + g * (float)sh[j];
  float4 o0 = {r[0], r[1], r[2], r[3]}, o1 = {r[4], r[5], r[6], r[7]};
  *(float4*)&out[tb + hb] = o0;
  *(float4*)&out[tb + hb + 4] = o1;
}

extern "C" void kernel_launch(void* const* d_in, const int* in_sizes, int n_in,
                              void* d_out, int out_size, void* d_ws, size_t ws_size,
                              hipStream_t stream) {
  const float* X   = (const float*)d_in[0];
  const float* Wr  = (const float*)d_in[1];
  const float* Wgu = (const float*)d_in[2];
  const float* Wd  = (const float*)d_in[3];
  const float* Wsg = (const float*)d_in[4];
  const float* Wsu = (const float*)d_in[5];
  const float* Wsd = (const float*)d_in[6];
  const float* Wge = (const float*)d_in[7];
  float* out = (float*)d_out;

  size_t off = 0;
  auto alloc = [&](size_t bytes) -> void* {
    void* p = (char*)d_ws + off;
    off += (bytes + 255) & ~(size_t)255;
    return p;
  };
  bf16* Xbf    = (bf16*)alloc((size_t)T_TOK * H_DIM * 2);
  bf16* WguT   = (bf16*)alloc((size_t)NE * 2 * IMOE * H_DIM * 2);
  bf16* WdT    = (bf16*)alloc((size_t)NE * H_DIM * IMOE * 2);
  bf16* WsguT  = (bf16*)alloc((size_t)2 * ISH * H_DIM * 2);
  bf16* WsdT   = (bf16*)alloc((size_t)H_DIM * ISH * 2);
  bf16* act    = (bf16*)alloc((size_t)TK * IMOE * 2);
  bf16* act_sh = (bf16*)alloc((size_t)T_TOK * ISH * 2);
  bf16* eout   = (bf16*)alloc((size_t)TK * H_DIM * 2);
  bf16* shout  = (bf16*)alloc((size_t)T_TOK * H_DIM * 2);
  float* tw    = (float*)alloc((size_t)T_TOK * TOPK * 4);
  int*   tidx  = (int*)alloc((size_t)T_TOK * TOPK * 4);
  float* gsig  = (float*)alloc((size_t)T_TOK * 4);
  int*   counts= (int*)alloc(64);
  int*   offs  = (int*)alloc(128);
  int*   fill  = (int*)alloc(64);
  int*   rowtok= (int*)alloc((size_t)TK * 4);
  int*   rowpos= (int*)alloc((size_t)TK * 4);
  int*   ttab  = (int*)alloc((size_t)MAXT256 * 3 * 4);
  int*   ntl   = (int*)alloc(64);
  if (off > ws_size) return;

  init_kernel<<<1, 32, 0, stream>>>(counts, fill);

  cvt_transpose64<<<dim3(2 * IMOE / 64, H_DIM / 64, NE), 256, 0, stream>>>(
      Wgu, WguT, H_DIM, 2 * IMOE, (size_t)H_DIM * 2 * IMOE, (size_t)H_DIM * 2 * IMOE, IMOE, 0);
  cvt_transpose64<<<dim3(H_DIM / 64, IMOE / 64, NE), 256, 0, stream>>>(
      Wd, WdT, IMOE, H_DIM, (size_t)IMOE * H_DIM, (size_t)IMOE * H_DIM, -1, 0);
  cvt_transpose64<<<dim3(ISH / 64, H_DIM / 64, 1), 256, 0, stream>>>(
      Wsg, WsguT, H_DIM, ISH, 0, 0, ISH, 0);
  cvt_transpose64<<<dim3(ISH / 64, H_DIM / 64, 1), 256, 0, stream>>>(
      Wsu, WsguT, H_DIM, ISH, 0, 0, ISH, 128);
  cvt_transpose64<<<dim3(H_DIM / 64, ISH / 64, 1), 256, 0, stream>>>(
      Wsd, WsdT, ISH, H_DIM, 0, 0, -1, 0);

  router_kernel<<<T_TOK / 4, 256, 0, stream>>>(X, Wr, Wge, Xbf, tw, tidx, gsig);
  hist_kernel<<<TK / 256, 256, 0, stream>>>(tidx, counts);
  scan_kernel<<<1, 64, 0, stream>>>(counts, offs, fill, ttab, ntl);
  scatter_kernel<<<TK / 256, 256, 0, stream>>>(tidx, offs, fill, rowtok, rowpos);

  // grouped GEMM 1 + fused swiglu: [TK,2048] x [2048,2816] -> act [TK,1408]
  gemm256<<<dim3(MAXT256, 2 * IMOE / 256), 512, 0, stream>>>(
      Xbf, H_DIM, WguT, (size_t)2 * IMOE * H_DIM, H_DIM,
      act, IMOE, rowtok, ttab, ntl, 0, 1);

  // grouped GEMM 2: act [TK,1408] x [1408,2048] -> eout
  gemm256<<<dim3(MAXT256, H_DIM / 256), 512, 0, stream>>>(
      act, IMOE, WdT, (size_t)H_DIM * IMOE, IMOE,
      eout, H_DIM, nullptr, ttab, ntl, 0, 0);

  // shared expert: dense gate_up + fused swiglu -> act_sh [8192,5632]
  gemm256<<<dim3(T_TOK / 256, 2 * ISH / 256), 512, 0, stream>>>(
      Xbf, H_DIM, WsguT, 0, H_DIM,
      act_sh, ISH, nullptr, nullptr, nullptr, T_TOK, 1);
  gemm256<<<dim3(T_TOK / 256, H_DIM / 256), 512, 0, stream>>>(
      act_sh, ISH, WsdT, 0, ISH,
      shout, H_DIM, nullptr, nullptr, nullptr, T_TOK, 0);

  combine_kernel<<<T_TOK, 256, 0, stream>>>(tw, rowpos, eout, shout, gsig, out);
}

// Round 6
// 1462.477 us; speedup vs baseline: 1.9264x; 1.0151x over previous
//
#include <hip/hip_runtime.h>
#include <hip/hip_bf16.h>

#define T_TOK 8192
#define H_DIM 2048
#define NE    16
#define TOPK  4
#define IMOE  1408
#define ISH   5632
#define TK    (T_TOK*TOPK)
#define MAXT256 ((TK/256)+NE)

typedef __bf16 bf16;
typedef __attribute__((ext_vector_type(8))) __bf16 bf16x8;
typedef __attribute__((ext_vector_type(4))) float  f32x4;

__device__ __forceinline__ void gload_lds16(const bf16* g, bf16* l) {
  __builtin_amdgcn_global_load_lds((const __attribute__((address_space(1))) void*)g,
                                   (__attribute__((address_space(3))) void*)l, 16, 0, 0);
}
#define MEMFENCE asm volatile("" ::: "memory")
#define BARRIER  do { MEMFENCE; __builtin_amdgcn_s_barrier(); MEMFENCE; } while (0)
#define VMCNT4   asm volatile("s_waitcnt vmcnt(4)" ::: "memory")

// ---------------- fp32 [R][C] -> bf16 [C'][R] transpose, 64x64 tiles, vectorized.
// Inputs are read-once: nontemporal loads keep L3 for the bf16 outputs.
__global__ __launch_bounds__(256) void cvt_transpose64(const float* __restrict__ in,
                                                       bf16* __restrict__ out,
                                                       int R, int C,
                                                       size_t strideIn, size_t strideOut,
                                                       int split, int base_off) {
  __shared__ float tile[64][65];
  const float* inm = in + (size_t)blockIdx.z * strideIn;
  bf16* outm = out + (size_t)blockIdx.z * strideOut;
  int c0 = blockIdx.x * 64, r0 = blockIdx.y * 64;
  int tid = threadIdx.x;
  int rr = tid >> 4, cc4 = (tid & 15) * 4;
  #pragma unroll
  for (int i = 0; i < 4; ++i) {
    f32x4 v = __builtin_nontemporal_load(
        (const f32x4*)&inm[(size_t)(r0 + rr + i * 16) * C + c0 + cc4]);
    tile[rr + i * 16][cc4 + 0] = v.x;
    tile[rr + i * 16][cc4 + 1] = v.y;
    tile[rr + i * 16][cc4 + 2] = v.z;
    tile[rr + i * 16][cc4 + 3] = v.w;
  }
  __syncthreads();
  int r8 = (tid & 7) * 8;
  #pragma unroll
  for (int i = 0; i < 2; ++i) {
    int c = (tid >> 3) + i * 32;
    int co = c0 + c;
    int orow;
    if (split < 0) orow = co;
    else {
      int cl = co, o = base_off;
      if (cl >= split) { cl -= split; o += 128; }
      orow = ((cl >> 7) << 8) + o + (cl & 127);
    }
    bf16x8 v;
    #pragma unroll
    for (int j = 0; j < 8; ++j) v[j] = (bf16)tile[r8 + j][c];
    *(bf16x8*)&outm[(size_t)orow * R + r0 + r8] = v;
  }
}

// ---------------- zero small counters
__global__ void init_kernel(int* counts, int* fill) {
  int i = threadIdx.x;
  if (i < NE) { counts[i] = 0; fill[i] = 0; }
}

// ---------------- router: wave-per-token, fp64 logits, lane-parallel top-4, no atomics
__global__ __launch_bounds__(256) void router_kernel(const float* __restrict__ X,
                                                     const float* __restrict__ Wr,
                                                     const float* __restrict__ wgate,
                                                     bf16* __restrict__ Xbf,
                                                     float* __restrict__ topk_w,
                                                     int* __restrict__ topk_idx,
                                                     float* __restrict__ gate_sig) {
  const int wv = threadIdx.x >> 6, lane = threadIdx.x & 63;
  const int t = blockIdx.x * 4 + wv;
  const float* x = X + (size_t)t * H_DIM;
  float xf[32];
  #pragma unroll
  for (int j = 0; j < 32; ++j) xf[j] = x[j * 64 + lane];
  #pragma unroll
  for (int j = 0; j < 32; ++j) Xbf[(size_t)t * H_DIM + j * 64 + lane] = (bf16)xf[j];

  double lg = 0.0;
  for (int e = 0; e < NE + 1; ++e) {
    const float* w = (e < NE) ? (Wr + (size_t)e * H_DIM) : wgate;
    double s0 = 0.0, s1 = 0.0;
    #pragma unroll
    for (int j = 0; j < 32; j += 2) {
      s0 += (double)xf[j] * (double)w[j * 64 + lane];
      s1 += (double)xf[j + 1] * (double)w[(j + 1) * 64 + lane];
    }
    double s = s0 + s1;
    #pragma unroll
    for (int off = 32; off; off >>= 1) s += __shfl_xor(s, off);
    if (lane == e) lg = s;
  }

  double v = (lane < NE) ? lg : -1e300;
  double m = v;
  #pragma unroll
  for (int off = 32; off; off >>= 1) m = fmax(m, __shfl_xor(m, off));
  double ev = (lane < NE) ? exp(v - m) : 0.0;
  double den = ev;
  #pragma unroll
  for (int off = 32; off; off >>= 1) den += __shfl_xor(den, off);

  double vv = v;
  int widx = 0; double wval = 0.0;
  for (int k = 0; k < TOPK; ++k) {
    double bv = vv; int bi = lane;
    #pragma unroll
    for (int off = 32; off; off >>= 1) {
      double ov = __shfl_xor(bv, off);
      int oi = __shfl_xor(bi, off);
      if (ov > bv || (ov == bv && oi < bi)) { bv = ov; bi = oi; }
    }
    double evb = __shfl(ev, bi);
    if (lane == k) { widx = bi; wval = evb / den; }
    if (lane == bi) vv = -1e300;
  }
  if (lane < TOPK) {
    topk_idx[t * TOPK + lane] = widx;
    topk_w[t * TOPK + lane] = (float)wval;
  }
  if (lane == NE) gate_sig[t] = (float)(1.0 / (1.0 + exp(-lg)));
}

// ---------------- histogram (LDS-local, 16 atomics/block)
__global__ __launch_bounds__(256) void hist_kernel(const int* __restrict__ tidx,
                                                   int* __restrict__ counts) {
  __shared__ int h[NE];
  if (threadIdx.x < NE) h[threadIdx.x] = 0;
  __syncthreads();
  int gid = blockIdx.x * 256 + threadIdx.x;
  atomicAdd(&h[tidx[gid]], 1);
  __syncthreads();
  if (threadIdx.x < NE) atomicAdd(&counts[threadIdx.x], h[threadIdx.x]);
}

// ---------------- prefix scan + 256-row grouped tile table
__global__ void scan_kernel(const int* __restrict__ counts, int* __restrict__ offs,
                            int* __restrict__ fill, int* __restrict__ ttab,
                            int* __restrict__ ntl) {
  if (threadIdx.x != 0) return;
  int off = 0;
  for (int e = 0; e < NE; ++e) { offs[e] = off; off += counts[e]; fill[e] = 0; }
  offs[NE] = off;
  int n = 0;
  for (int e = 0; e < NE; ++e) {
    int cnt = counts[e], end_ = offs[e] + cnt;
    for (int m = 0; m < cnt; m += 256) {
      ttab[n * 3 + 0] = e;
      ttab[n * 3 + 1] = offs[e] + m;
      ttab[n * 3 + 2] = end_;
      ++n;
    }
  }
  *ntl = n;
}

// ---------------- scatter: hierarchical rank (ballot) + 16 atomics/block
__global__ __launch_bounds__(256) void scatter_kernel(const int* __restrict__ topk_idx,
                                                      const int* __restrict__ offs,
                                                      int* __restrict__ fill,
                                                      int* __restrict__ row_token,
                                                      int* __restrict__ row_pos) {
  __shared__ int wc[4][NE];
  __shared__ int wbase[4][NE];
  __shared__ int bbase[NE];
  const int tid = threadIdx.x, wv = tid >> 6, lane = tid & 63;
  const int gid = blockIdx.x * 256 + tid;
  const int e = topk_idx[gid];
  int rank = 0;
  #pragma unroll
  for (int ex = 0; ex < NE; ++ex) {
    unsigned long long b = __ballot(e == ex);
    if (e == ex) rank = __popcll(b & ((1ull << lane) - 1));
    if (lane == 0) wc[wv][ex] = __popcll(b);
  }
  __syncthreads();
  if (tid < NE) {
    int s = 0;
    #pragma unroll
    for (int w = 0; w < 4; ++w) { wbase[w][tid] = s; s += wc[w][tid]; }
    bbase[tid] = atomicAdd(&fill[tid], s);
  }
  __syncthreads();
  int pos = offs[e] + bbase[e] + wbase[wv][e] + rank;
  row_token[pos] = gid >> 2;
  row_pos[gid] = pos;
}

__device__ __forceinline__ void mfma_cluster(f32x4 (&a)[4][2], bf16x8 (&A)[4][2],
                                             bf16x8 (&B)[2][2]) {
  __builtin_amdgcn_s_setprio(1);
  #pragma unroll
  for (int m = 0; m < 4; ++m)
    #pragma unroll
    for (int n = 0; n < 2; ++n) {
      a[m][n] = __builtin_amdgcn_mfma_f32_16x16x32_bf16(A[m][0], B[n][0], a[m][n], 0, 0, 0);
      a[m][n] = __builtin_amdgcn_mfma_f32_16x16x32_bf16(A[m][1], B[n][1], a[m][n], 0, 0, 0);
    }
  __builtin_amdgcn_s_setprio(0);
}

// ---------------- 256x256 bf16 MFMA GEMM, counted-vmcnt AFTER the MFMA cluster.
// Steady-state invariant (per wave, loads counted as instructions):
//   entering f1: 4 outstanding (B1,A1 of current buf).
//   f1: +2 (A0 nb), MFMA, vmcnt4 -> drains B1(cb)   [read at f2]
//   f2: +2 (B0 nb), MFMA, vmcnt4 -> drains A1(cb)   [read at f3]
//   f3: +2 (B1 nb), MFMA, no wait
//   f4: +2 (A1 nb), MFMA, vmcnt4 -> drains A0,B0(nb) [read at next f1]
__global__ __launch_bounds__(512, 2) void gemm256(
    const bf16* __restrict__ A, int lda,
    const bf16* __restrict__ B, size_t strideB, int Ktot,
    bf16* __restrict__ C, int ldc,
    const int* __restrict__ row_token,
    const int* __restrict__ tile_tab, const int* __restrict__ n_tiles,
    int Mdense, int fuse_swiglu) {
  unsigned total = gridDim.x * gridDim.y;
  unsigned id = blockIdx.y * gridDim.x + blockIdx.x;
  unsigned qd = total >> 3, rm = total & 7, xc = id & 7, hid = id >> 3;
  unsigned swz = (xc < rm ? xc * (qd + 1) : rm * (qd + 1) + (xc - rm) * qd) + hid;
  int mt = (int)(swz % gridDim.x), nt = (int)(swz / gridDim.x);

  int e, row_start, row_end;
  if (tile_tab) {
    if (mt >= *n_tiles) return;
    e = tile_tab[mt * 3 + 0];
    row_start = tile_tab[mt * 3 + 1];
    row_end = tile_tab[mt * 3 + 2];
  } else {
    e = 0; row_start = mt * 256; row_end = Mdense;
  }
  const bf16* Bp = B + (size_t)e * strideB;

  __shared__ bf16 smA[2][2][8192];   // [buf][half][128*64]
  __shared__ bf16 smB[2][2][8192];

  const int tid = threadIdx.x;
  const int wave = tid >> 6;
  const int lane = tid & 63;

  unsigned aoff[2][2], boff[2][2];
  {
    int csrc = (((tid & 7) ^ ((tid >> 3) & 7)) << 3);
    #pragma unroll
    for (int h = 0; h < 2; ++h)
      #pragma unroll
      for (int j = 0; j < 2; ++j) {
        int rho = j * 64 + (tid >> 3);
        int r = row_start + h * 128 + rho;
        if (r > row_end - 1) r = row_end - 1;
        int sr = row_token ? row_token[r] : r;
        aoff[h][j] = (unsigned)sr * (unsigned)lda + (unsigned)csrc;
        boff[h][j] = (unsigned)(nt * 256 + h * 128 + rho) * (unsigned)Ktot + (unsigned)csrc;
      }
  }

  auto STAGE_A = [&](int bufi, int h, int tt) {
    gload_lds16(A + (size_t)(aoff[h][0] + (unsigned)tt * 64u), &smA[bufi][h][wave << 9]);
    gload_lds16(A + (size_t)(aoff[h][1] + (unsigned)tt * 64u), &smA[bufi][h][4096 + (wave << 9)]);
  };
  auto STAGE_B = [&](int bufi, int h, int tt) {
    gload_lds16(Bp + (size_t)(boff[h][0] + (unsigned)tt * 64u), &smB[bufi][h][wave << 9]);
    gload_lds16(Bp + (size_t)(boff[h][1] + (unsigned)tt * 64u), &smB[bufi][h][4096 + (wave << 9)]);
  };

  const int warow = ((wave >> 2) << 6) + (lane & 15);
  const int wbrow = ((wave & 3) << 5) + (lane & 15);
  const int q4 = lane >> 4;
  auto LDA_ = [&](int bufi, int h, int m, int kk) -> bf16x8 {
    int row = warow + m * 16;
    int c = (kk * 4 + q4) ^ (row & 7);
    return *(const bf16x8*)&smA[bufi][h][row * 64 + c * 8];
  };
  auto LDB_ = [&](int bufi, int h, int n, int kk) -> bf16x8 {
    int row = wbrow + n * 16;
    int c = (kk * 4 + q4) ^ (row & 7);
    return *(const bf16x8*)&smB[bufi][h][row * 64 + c * 8];
  };

  f32x4 acc[4][4][2];
  #pragma unroll
  for (int q = 0; q < 4; ++q)
    #pragma unroll
    for (int m = 0; m < 4; ++m)
      #pragma unroll
      for (int n = 0; n < 2; ++n) acc[q][m][n] = (f32x4){0.f, 0.f, 0.f, 0.f};

  bf16x8 Ar[4][2], Br0[2][2], Br1[2][2];

#define RD_A(BUF, H) do { \
    _Pragma("unroll") for (int m_ = 0; m_ < 4; ++m_) { \
      Ar[m_][0] = LDA_(BUF, H, m_, 0); Ar[m_][1] = LDA_(BUF, H, m_, 1); } } while (0)
#define RD_B(BUF, H, DST) do { \
    _Pragma("unroll") for (int n_ = 0; n_ < 2; ++n_) { \
      DST[n_][0] = LDB_(BUF, H, n_, 0); DST[n_][1] = LDB_(BUF, H, n_, 1); } } while (0)

#define DO_TILE(CB, NB, TS) do { \
    /* f1: q0=(A0,B0); stage A0(NB); post-MFMA wait drains B1(CB) for f2 */ \
    RD_A(CB, 0); RD_B(CB, 0, Br0); \
    STAGE_A(NB, 0, TS); \
    BARRIER; \
    mfma_cluster(acc[0], Ar, Br0); \
    VMCNT4; \
    BARRIER; \
    /* f2: q1=(A0,B1); stage B0(NB); post-MFMA wait drains A1(CB) for f3 */ \
    RD_B(CB, 1, Br1); \
    STAGE_B(NB, 0, TS); \
    BARRIER; \
    mfma_cluster(acc[1], Ar, Br1); \
    VMCNT4; \
    BARRIER; \
    /* f3: q2=(A1,B1); stage B1(NB) */ \
    RD_A(CB, 1); \
    STAGE_B(NB, 1, TS); \
    BARRIER; \
    mfma_cluster(acc[2], Ar, Br1); \
    BARRIER; \
    /* f4: q3=(A1,B0); stage A1(NB); post-MFMA wait drains A0,B0(NB) for next f1 */ \
    STAGE_A(NB, 1, TS); \
    mfma_cluster(acc[3], Ar, Br0); \
    VMCNT4; \
    BARRIER; \
  } while (0)

  STAGE_A(0, 0, 0); STAGE_B(0, 0, 0); STAGE_B(0, 1, 0); STAGE_A(0, 1, 0);
  VMCNT4; BARRIER;

  const int nk = Ktot >> 6;
  for (int it = 0; it < nk; it += 2) {
    const int ts1 = it + 1;
    const int ts2 = (it + 2 < nk) ? it + 2 : it + 1;
    DO_TILE(0, 1, ts1);
    DO_TILE(1, 0, ts2);
  }
#undef DO_TILE
#undef RD_A
#undef RD_B

  const int er = (lane >> 4) * 4;
  if (fuse_swiglu) {
    const int cb0 = nt * 128 + ((wave & 3) << 5) + (lane & 15);
    #pragma unroll
    for (int qi = 0; qi < 2; ++qi) {
      const int qg = qi ? 3 : 0, qu = qi ? 2 : 1;
      int rb = row_start + qi * 128 + ((wave >> 2) << 6) + er;
      #pragma unroll
      for (int m = 0; m < 4; ++m)
        #pragma unroll
        for (int n = 0; n < 2; ++n)
          #pragma unroll
          for (int j = 0; j < 4; ++j) {
            int r = rb + m * 16 + j;
            if (r < row_end) {
              float g = acc[qg][m][n][j];
              float u = acc[qu][m][n][j];
              float s = g / (1.f + __expf(-g));
              C[(size_t)r * ldc + cb0 + n * 16] = (bf16)(s * u);
            }
          }
    }
  } else {
    const int qr[4] = {0, 0, 1, 1}, qc[4] = {0, 1, 1, 0};
    #pragma unroll
    for (int q = 0; q < 4; ++q) {
      int rb = row_start + qr[q] * 128 + ((wave >> 2) << 6) + er;
      int cb0 = nt * 256 + qc[q] * 128 + ((wave & 3) << 5) + (lane & 15);
      #pragma unroll
      for (int m = 0; m < 4; ++m)
        #pragma unroll
        for (int n = 0; n < 2; ++n)
          #pragma unroll
          for (int j = 0; j < 4; ++j) {
            int r = rb + m * 16 + j;
            if (r < row_end) C[(size_t)r * ldc + cb0 + n * 16] = (bf16)acc[q][m][n][j];
          }
    }
  }
}

// ---------------- combine
__global__ __launch_bounds__(256) void combine_kernel(const float* __restrict__ topk_w,
                                                      const int* __restrict__ row_pos,
                                                      const bf16* __restrict__ eout,
                                                      const bf16* __restrict__ shout,
                                                      const float* __restrict__ gate_sig,
                                                      float* __restrict__ out) {
  int t = blockIdx.x;
  float w0 = topk_w[t * 4 + 0], w1 = topk_w[t * 4 + 1];
  float w2 = topk_w[t * 4 + 2], w3 = topk_w[t * 4 + 3];
  size_t p0 = (size_t)row_pos[t * 4 + 0] * H_DIM;
  size_t p1 = (size_t)row_pos[t * 4 + 1] * H_DIM;
  size_t p2 = (size_t)row_pos[t * 4 + 2] * H_DIM;
  size_t p3 = (size_t)row_pos[t * 4 + 3] * H_DIM;
  float g = gate_sig[t];
  size_t tb = (size_t)t * H_DIM;
  size_t hb = (size_t)threadIdx.x * 8;
  bf16x8 a0 = *(const bf16x8*)&eout[p0 + hb];
  bf16x8 a1 = *(const bf16x8*)&eout[p1 + hb];
  bf16x8 a2 = *(const bf16x8*)&eout[p2 + hb];
  bf16x8 a3 = *(const bf16x8*)&eout[p3 + hb];
  bf16x8 sh = *(const bf16x8*)&shout[tb + hb];
  float r[8];
  #pragma unroll
  for (int j = 0; j < 8; ++j)
    r[j] = w0 * (float)a0[j] + w1 * (float)a1[j] + w2 * (float)a2[j]
         + w3 * (float)a3[j] + g * (float)sh[j];
  float4 o0 = {r[0], r[1], r[2], r[3]}, o1 = {r[4], r[5], r[6], r[7]};
  *(float4*)&out[tb + hb] = o0;
  *(float4*)&out[tb + hb + 4] = o1;
}

extern "C" void kernel_launch(void* const* d_in, const int* in_sizes, int n_in,
                              void* d_out, int out_size, void* d_ws, size_t ws_size,
                              hipStream_t stream) {
  const float* X   = (const float*)d_in[0];
  const float* Wr  = (const float*)d_in[1];
  const float* Wgu = (const float*)d_in[2];
  const float* Wd  = (const float*)d_in[3];
  const float* Wsg = (const float*)d_in[4];
  const float* Wsu = (const float*)d_in[5];
  const float* Wsd = (const float*)d_in[6];
  const float* Wge = (const float*)d_in[7];
  float* out = (float*)d_out;

  size_t off = 0;
  auto alloc = [&](size_t bytes) -> void* {
    void* p = (char*)d_ws + off;
    off += (bytes + 255) & ~(size_t)255;
    return p;
  };
  bf16* Xbf    = (bf16*)alloc((size_t)T_TOK * H_DIM * 2);
  bf16* WguT   = (bf16*)alloc((size_t)NE * 2 * IMOE * H_DIM * 2);
  bf16* WdT    = (bf16*)alloc((size_t)NE * H_DIM * IMOE * 2);
  bf16* WsguT  = (bf16*)alloc((size_t)2 * ISH * H_DIM * 2);
  bf16* WsdT   = (bf16*)alloc((size_t)H_DIM * ISH * 2);
  bf16* act    = (bf16*)alloc((size_t)TK * IMOE * 2);
  bf16* act_sh = (bf16*)alloc((size_t)T_TOK * ISH * 2);
  bf16* eout   = (bf16*)alloc((size_t)TK * H_DIM * 2);
  bf16* shout  = (bf16*)alloc((size_t)T_TOK * H_DIM * 2);
  float* tw    = (float*)alloc((size_t)T_TOK * TOPK * 4);
  int*   tidx  = (int*)alloc((size_t)T_TOK * TOPK * 4);
  float* gsig  = (float*)alloc((size_t)T_TOK * 4);
  int*   counts= (int*)alloc(64);
  int*   offs  = (int*)alloc(128);
  int*   fill  = (int*)alloc(64);
  int*   rowtok= (int*)alloc((size_t)TK * 4);
  int*   rowpos= (int*)alloc((size_t)TK * 4);
  int*   ttab  = (int*)alloc((size_t)MAXT256 * 3 * 4);
  int*   ntl   = (int*)alloc(64);
  if (off > ws_size) return;

  init_kernel<<<1, 32, 0, stream>>>(counts, fill);

  // Transposes ordered so the tensors needed FIRST by the GEMM chain are
  // written LAST (stay L3-resident): WsdT, WsguT, WdT early; WguT last.
  cvt_transpose64<<<dim3(H_DIM / 64, ISH / 64, 1), 256, 0, stream>>>(
      Wsd, WsdT, ISH, H_DIM, 0, 0, -1, 0);
  cvt_transpose64<<<dim3(ISH / 64, H_DIM / 64, 1), 256, 0, stream>>>(
      Wsg, WsguT, H_DIM, ISH, 0, 0, ISH, 0);
  cvt_transpose64<<<dim3(ISH / 64, H_DIM / 64, 1), 256, 0, stream>>>(
      Wsu, WsguT, H_DIM, ISH, 0, 0, ISH, 128);
  cvt_transpose64<<<dim3(H_DIM / 64, IMOE / 64, NE), 256, 0, stream>>>(
      Wd, WdT, IMOE, H_DIM, (size_t)IMOE * H_DIM, (size_t)IMOE * H_DIM, -1, 0);
  cvt_transpose64<<<dim3(2 * IMOE / 64, H_DIM / 64, NE), 256, 0, stream>>>(
      Wgu, WguT, H_DIM, 2 * IMOE, (size_t)H_DIM * 2 * IMOE, (size_t)H_DIM * 2 * IMOE, IMOE, 0);

  router_kernel<<<T_TOK / 4, 256, 0, stream>>>(X, Wr, Wge, Xbf, tw, tidx, gsig);
  hist_kernel<<<TK / 256, 256, 0, stream>>>(tidx, counts);
  scan_kernel<<<1, 64, 0, stream>>>(counts, offs, fill, ttab, ntl);
  scatter_kernel<<<TK / 256, 256, 0, stream>>>(tidx, offs, fill, rowtok, rowpos);

  // grouped GEMM 1 + fused swiglu: [TK,2048] x [2048,2816] -> act [TK,1408]
  gemm256<<<dim3(MAXT256, 2 * IMOE / 256), 512, 0, stream>>>(
      Xbf, H_DIM, WguT, (size_t)2 * IMOE * H_DIM, H_DIM,
      act, IMOE, rowtok, ttab, ntl, 0, 1);

  // grouped GEMM 2: act [TK,1408] x [1408,2048] -> eout (act still L3-hot)
  gemm256<<<dim3(MAXT256, H_DIM / 256), 512, 0, stream>>>(
      act, IMOE, WdT, (size_t)H_DIM * IMOE, IMOE,
      eout, H_DIM, nullptr, ttab, ntl, 0, 0);

  // shared expert: dense gate_up + fused swiglu -> act_sh [8192,5632]
  gemm256<<<dim3(T_TOK / 256, 2 * ISH / 256), 512, 0, stream>>>(
      Xbf, H_DIM, WsguT, 0, H_DIM,
      act_sh, ISH, nullptr, nullptr, nullptr, T_TOK, 1);
  gemm256<<<dim3(T_TOK / 256, H_DIM / 256), 512, 0, stream>>>(
      act_sh, ISH, WsdT, 0, ISH,
      shout, H_DIM, nullptr, nullptr, nullptr, T_TOK, 0);

  combine_kernel<<<T_TOK, 256, 0, stream>>>(tw, rowpos, eout, shout, gsig, out);
}